// Round 3
// baseline (1048.798 us; speedup 1.0000x reference)
//
#include <hip/hip_runtime.h>
#include <stdint.h>

// ---------------- problem constants ----------------
#define D_    1024
#define H_    4
#define HD_   256
#define WIN_  128
#define NPM_  4
#define B_    2
#define L_    4096
#define LT_   4100     // L + NPMEM
#define LTP_  4112     // padded row length for V^T (16B-aligned rows)
#define QKL_  3072     // fused qkv row stride

typedef __attribute__((ext_vector_type(8))) short short8;   // 8 bf16 (4 VGPRs)
typedef __attribute__((ext_vector_type(4))) float f32x4;    // MFMA acc

__device__ __forceinline__ short f2bf(float f) {
  union { float f; uint32_t u; } v; v.f = f;
  uint32_t r = v.u + 0x7FFFu + ((v.u >> 16) & 1u);   // RNE
  return (short)(r >> 16);
}
__device__ __forceinline__ float bf2f(short h) {
  union { uint32_t u; float f; } v; v.u = ((uint32_t)(uint16_t)h) << 16;
  return v.f;
}

// ---- async global->LDS (16B per lane; dest = wave-uniform base + lane*16) ----
typedef __attribute__((address_space(1))) void GAS;
typedef __attribute__((address_space(3))) void LAS;
__device__ __forceinline__ void gl16(const void* g, void* l) {
  __builtin_amdgcn_global_load_lds((GAS*)g, (LAS*)l, 16, 0, 0);
}
template<int N> __device__ __forceinline__ void waitvmN() {
  if constexpr (N == 8)      asm volatile("s_waitcnt vmcnt(8)" ::: "memory");
  else if constexpr (N == 6) asm volatile("s_waitcnt vmcnt(6)" ::: "memory");
  else if constexpr (N == 4) asm volatile("s_waitcnt vmcnt(4)" ::: "memory");
  else if constexpr (N == 3) asm volatile("s_waitcnt vmcnt(3)" ::: "memory");
  else                       asm volatile("s_waitcnt vmcnt(0)" ::: "memory");
}

// epilogue kinds
#define EP_BF16 0   // store bf16, no bias
#define EP_F32B 1   // store f32 + bias
#define EP_GATE 2   // g=sigmoid(acc+bias); store bf16( aux_bf16[r][c] * g )
#define EP_SILU 3   // v=acc+bias; store bf16( v*sigmoid(v) )
#define EP_RES  4   // store f32( acc + bias + aux_f32[r][c] )
#define EP_CORE 5   // store bf16, skipping pmem rows: row b*LT+t -> b*L+(t-NPM)

// ---------------- 128-tile GEMM: C(MxN) = A(MxK) * B^T(NxK), bf16 in, f32 acc ----
// m97-class structure upgraded: staging via global_load_lds (width 16) direct to
// LDS — the LDS destination was already linear in tid (wave-uniform + lane*16),
// with the zero-conflict XOR swizzle applied on the GLOBAL source side, so the
// gl16 conversion preserves the exact byte layout of the proven reg-staged path.
// 4 LDS buffers, stage issued 2 K-steps ahead, counted vmcnt(2G) (never drains
// to 0 in steady state), ONE raw s_barrier per K-step. Race safety: barrier
// bounds wave skew to one K-step; stage(i+2) writes buf[(i+2)&3] while readers
// hold buf[i&3]/buf[(i-1)&3] (distinct mod 4); ds_reads are lgkm-consumed
// before each wave's next barrier (MFMA operand dependency).
template<int EP, int TM>
__global__ __launch_bounds__(256, 2)
void gemm_bt(const short* __restrict__ A, int lda,
             const short* __restrict__ Bt,
             void* __restrict__ Cp, int ldc,
             const float* __restrict__ bias,
             const void* __restrict__ aux, int ldaux,
             int M, int N, int K)
{
  constexpr int WM = TM / 2;          // wave rows
  constexpr int MT = WM / 16;         // m-frags per wave
  constexpr int BUFSZ = (TM + 128) * 32;   // shorts per LDS buffer (A tile + B tile)
  constexpr int G = (TM == 128) ? 4 : 3;   // gl16 per thread per K-step
  __shared__ __attribute__((aligned(16))) short lds[4 * BUFSZ];
  const int tid  = threadIdx.x;
  const int lane = tid & 63, wave = tid >> 6;
  const int lhi  = lane >> 4, llo = lane & 15;
  const int m0 = blockIdx.x * TM, n0 = blockIdx.y * 128;
  const int mw = (wave >> 1) * WM, nw = (wave & 1) * 64;

  // staging: LDS row = tid>>2 (64B rows), phys seg = tid&3 holds global seg
  // (tid&3)^((tid>>3)&3); frag read recovers with lhi ^ ((llo>>1)&3).
  const int srow = tid >> 2;                       // 0..63
  const int sg   = (tid & 3) ^ ((tid >> 3) & 3);   // swizzled global 16B-seg
  const short* pA0 = A + (size_t)min(m0 + srow, M - 1) * lda + sg * 8;
  const short* pA1 = (TM == 128) ? A + (size_t)min(m0 + srow + 64, M - 1) * lda + sg * 8 : pA0;
  const short* pB0 = Bt + (size_t)(n0 + srow) * K + sg * 8;
  const short* pB1 = Bt + (size_t)(n0 + srow + 64) * K + sg * 8;

  const int segoff = (lhi ^ ((llo >> 1) & 3)) * 8;  // frag-read swizzle

  auto stage = [&](int b, int i) {
    const int k = i << 5;
    short* base = &lds[b * BUFSZ];
    gl16(pA0 + k, &base[tid * 8]);                          // A rows 0..63
    if constexpr (TM == 128) gl16(pA1 + k, &base[2048 + tid * 8]);  // A rows 64..127
    gl16(pB0 + k, &base[TM * 32 + tid * 8]);                // B rows 0..63
    gl16(pB1 + k, &base[TM * 32 + 2048 + tid * 8]);         // B rows 64..127
  };

  f32x4 acc[MT][4];
#pragma unroll
  for (int i = 0; i < MT; i++)
#pragma unroll
    for (int j = 0; j < 4; j++) acc[i][j] = f32x4{0.f, 0.f, 0.f, 0.f};

  const int NI = K >> 5;
  stage(0, 0);
  if (NI > 1) stage(1, 1);

  for (int i = 0; i < NI; i++) {
    if (i + 2 < NI) { stage((i + 2) & 3, i + 2); waitvmN<2 * G>(); }
    else if (i + 1 < NI) waitvmN<G>();
    else waitvmN<0>();
    __builtin_amdgcn_s_barrier();
    __builtin_amdgcn_sched_barrier(0);
    const short* bufp = &lds[(i & 3) * BUFSZ];
    short8 af[MT], bfr[4];
#pragma unroll
    for (int mt = 0; mt < MT; mt++)
      af[mt] = *(const short8*)&bufp[(mw + mt * 16 + llo) * 32 + segoff];
#pragma unroll
    for (int nt = 0; nt < 4; nt++)
      bfr[nt] = *(const short8*)&bufp[TM * 32 + (nw + nt * 16 + llo) * 32 + segoff];
#pragma unroll
    for (int mt = 0; mt < MT; mt++)
#pragma unroll
      for (int nt = 0; nt < 4; nt++)
        acc[mt][nt] = __builtin_amdgcn_mfma_f32_16x16x32_bf16(af[mt], bfr[nt], acc[mt][nt], 0, 0, 0);
  }

  const int gcb = n0 + nw;
#pragma unroll
  for (int mt = 0; mt < MT; mt++) {
    const int gr0 = m0 + mw + mt * 16 + lhi * 4;
#pragma unroll
    for (int nt = 0; nt < 4; nt++) {
      const int gc = gcb + nt * 16 + llo;
      float bv = 0.f;
      if constexpr (EP != EP_BF16 && EP != EP_CORE) bv = bias[gc];
#pragma unroll
      for (int r = 0; r < 4; r++) {
        const int gr = gr0 + r;
        if (gr >= M) continue;
        const float v = acc[mt][nt][r];
        if constexpr (EP == EP_CORE) {
          const int b   = gr >= LT_ ? 1 : 0;
          const int tok = gr - b * LT_;
          if (tok >= NPM_) {
            const int cr = b * L_ + (tok - NPM_);
            ((short*)Cp)[(size_t)cr * ldc + gc] = f2bf(v);
          }
          continue;
        }
        const size_t idx = (size_t)gr * ldc + gc;
        if constexpr (EP == EP_BF16) {
          ((short*)Cp)[idx] = f2bf(v);
        } else if constexpr (EP == EP_F32B) {
          ((float*)Cp)[idx] = v + bv;
        } else if constexpr (EP == EP_GATE) {
          float g  = 1.f / (1.f + __expf(-(v + bv)));
          float cv = bf2f(((const short*)aux)[(size_t)gr * ldaux + gc]);
          ((short*)Cp)[idx] = f2bf(cv * g);
        } else if constexpr (EP == EP_SILU) {
          float xx = v + bv;
          ((short*)Cp)[idx] = f2bf(xx / (1.f + __expf(-xx)));
        } else {
          ((float*)Cp)[idx] = v + bv + ((const float*)aux)[(size_t)gr * ldaux + gc];
        }
      }
    }
  }
}

// ---------------- fused cast+transpose of ALL weights (one launch) ----------------
struct TAll {
  const float* src[8];
  short* dst[8];
  int C[8];     // src cols (ld_in)
  int R[8];     // src rows (ld_out)
  int nbx[8];   // C/32
  int start[8]; // cumulative block offsets
};

__global__ __launch_bounds__(256)
void transpose_all(TAll t)
{
  __shared__ short tile[32][33];
  const int bid = blockIdx.x;
  int w = 0;
#pragma unroll
  for (int i = 1; i < 8; i++) w = (bid >= t.start[i]) ? i : w;
  const int rel = bid - t.start[w];
  const int nbx = t.nbx[w];
  const int bx = rel % nbx, by = rel / nbx;
  const float* src = t.src[w];
  short* dst = t.dst[w];
  const int ld_in = t.C[w], ld_out = t.R[w];
  const int r0 = by * 32, c0 = bx * 32;
  const int tx = threadIdx.x & 31, ty = threadIdx.x >> 5;
#pragma unroll
  for (int i = 0; i < 4; i++)
    tile[ty + i * 8][tx] = f2bf(src[(size_t)(r0 + ty + i * 8) * ld_in + c0 + tx]);
  __syncthreads();
#pragma unroll
  for (int i = 0; i < 4; i++)
    dst[(size_t)(c0 + ty + i * 8) * ld_out + r0 + tx] = tile[tx][ty + i * 8];
}

// ---------------- cast + transpose (strided/z-batched; used for V^T) ----------------
template<typename Tin>
__global__ __launch_bounds__(256)
void cast_transpose(const Tin* __restrict__ in, short* __restrict__ outp,
                    int R, int C, int ld_in, int ld_out,
                    int zdiv, size_t inA, size_t inB, size_t outA, size_t outB)
{
  __shared__ short tile[32][33];
  const int z = blockIdx.z;
  const Tin* src = in + (size_t)(z / zdiv) * inA + (size_t)(z % zdiv) * inB;
  short* dst = outp + (size_t)(z / zdiv) * outA + (size_t)(z % zdiv) * outB;
  const int r0 = blockIdx.y * 32, c0 = blockIdx.x * 32;
  const int tx = threadIdx.x & 31, ty = threadIdx.x >> 5;
#pragma unroll
  for (int i = 0; i < 4; i++) {
    int r = r0 + ty + i * 8, c = c0 + tx;
    short v = 0;
    if (r < R && c < C) {
      if constexpr (sizeof(Tin) == 4) v = f2bf((float)src[(size_t)r * ld_in + c]);
      else                            v = (short)src[(size_t)r * ld_in + c];
    }
    tile[ty + i * 8][tx] = v;
  }
  __syncthreads();
#pragma unroll
  for (int i = 0; i < 4; i++) {
    int c = c0 + ty + i * 8, r = r0 + tx;
    if (c < C && r < R) dst[(size_t)c * ld_out + r] = tile[tx][ty + i * 8];
  }
}

// ---------------- build xp = [pmem ; x] cast to bf16, rows = B*Lt ----------------
__global__ __launch_bounds__(256)
void build_xp_k(const float* __restrict__ x, const float* __restrict__ pmem,
                short* __restrict__ xp)
{
  int gid = blockIdx.x * 256 + threadIdx.x;
  int row = gid >> 8;
  int c4  = (gid & 255) * 4;
  int b   = row >= LT_ ? 1 : 0;
  int tok = row - b * LT_;
  const float* src = (tok < NPM_) ? (pmem + (size_t)tok * D_ + c4)
                                  : (x + ((size_t)b * L_ + tok - NPM_) * D_ + c4);
  float4 v = *(const float4*)src;
  short o[4] = {f2bf(v.x), f2bf(v.y), f2bf(v.z), f2bf(v.w)};
  *(short4*)&xp[(size_t)row * D_ + c4] = *(short4*)o;
}

// ---------------- combined[:, 0:2048] = cast(global_out | local_out) ----------------
__global__ __launch_bounds__(256)
void combined01_k(const float* __restrict__ go, const float* __restrict__ lo,
                  short* __restrict__ comb)
{
  int gid = blockIdx.x * 256 + threadIdx.x;
  int row = gid >> 9;
  int c4  = (gid & 511) * 4;
  const float* src = (c4 < D_) ? (go + (size_t)row * D_ + c4)
                               : (lo + (size_t)row * D_ + (c4 - D_));
  float4 v = *(const float4*)src;
  short o[4] = {f2bf(v.x), f2bf(v.y), f2bf(v.z), f2bf(v.w)};
  *(short4*)&comb[(size_t)row * 3072 + c4] = *(short4*)o;
}

// ---------------- in-place RoPE on fused qkv (bf16); folds 1/sqrt(HD) into q ----------------
__global__ __launch_bounds__(256)
void rope_kernel(short* __restrict__ qkv,
                 const float* __restrict__ cosp, const float* __restrict__ sinp)
{
  int gid = blockIdx.x * 256 + threadIdx.x;       // 8200 rows * 4 heads * 32 quads; exact
  int d   = (gid & 31) * 4;
  int h   = (gid >> 5) & 3;
  int row = gid >> 7;
  int t   = row >= LT_ ? row - LT_ : row;
  size_t base = (size_t)row * QKL_ + h * HD_ + d;
  float4 cl = *(const float4*)&cosp[(size_t)t * HD_ + d];
  float4 ch = *(const float4*)&cosp[(size_t)t * HD_ + d + 128];
  float4 sl = *(const float4*)&sinp[(size_t)t * HD_ + d];
  float4 sh = *(const float4*)&sinp[(size_t)t * HD_ + d + 128];
  short4 ql4 = *(const short4*)&qkv[base],        qh4 = *(const short4*)&qkv[base + 128];
  short4 kl4 = *(const short4*)&qkv[base + 1024], kh4 = *(const short4*)&qkv[base + 1152];
  const float SC = 1.f / 16.f;   // 1/sqrt(256)
  short oql[4], oqh[4], okl[4], okh[4];
#pragma unroll
  for (int j = 0; j < 4; j++) {
    float c0 = ((float*)&cl)[j], c1 = ((float*)&ch)[j];
    float s0 = ((float*)&sl)[j], s1 = ((float*)&sh)[j];
    float ql = bf2f(((short*)&ql4)[j]), qh = bf2f(((short*)&qh4)[j]);
    float kl = bf2f(((short*)&kl4)[j]), kh = bf2f(((short*)&kh4)[j]);
    oql[j] = f2bf((ql * c0 - qh * s0) * SC);
    oqh[j] = f2bf((qh * c1 + ql * s1) * SC);
    okl[j] = f2bf(kl * c0 - kh * s0);
    okh[j] = f2bf(kh * c1 + kl * s1);
  }
  *(short4*)&qkv[base]        = *(short4*)oql;
  *(short4*)&qkv[base + 128]  = *(short4*)oqh;
  *(short4*)&qkv[base + 1024] = *(short4*)okl;
  *(short4*)&qkv[base + 1152] = *(short4*)okh;
}

// ---------------- banded attention, MFMA; 64 queries/block, 192-key window ----------------
__global__ __launch_bounds__(256, 1)
void attn_kernel(const short* __restrict__ qkv, const short* __restrict__ vT,
                 short* __restrict__ outp)
{
  __shared__ short lKV[256 * 72];   // K chunk (64x264) or V^T chunk (256x72)
  __shared__ short lP[64 * 200];    // P: 64 q-rows x 192 keys (+pad)
  const int tid  = threadIdx.x;
  const int lane = tid & 63, wave = tid >> 6;
  const int lhi  = lane >> 4, llo = lane & 15;
  const int i0 = blockIdx.x * 64;
  const int h = blockIdx.y, b = blockIdx.z;
  const int kw0 = i0 - 128;
  const size_t vbase = (size_t)(b * H_ + h) * HD_ * LTP_;

  short8 qf[8];
  {
    int ic = min(i0 + wave * 16 + llo, LT_ - 1);
    const short* qrow = qkv + (size_t)(b * LT_ + ic) * QKL_ + h * HD_;
#pragma unroll
    for (int ks = 0; ks < 8; ks++)
      qf[ks] = *(const short8*)(qrow + ks * 32 + lhi * 8);
  }

  f32x4 S[12];
#pragma unroll
  for (int st = 0; st < 12; st++) S[st] = f32x4{0.f, 0.f, 0.f, 0.f};

  for (int kc = 0; kc < 3; kc++) {
    if (kc) __syncthreads();
    {
      int row = tid >> 2;
      int jc = min(max(kw0 + kc * 64 + row, 0), LT_ - 1);
      const short* krow = qkv + (size_t)(b * LT_ + jc) * QKL_ + 1024 + h * HD_;
#pragma unroll
      for (int it = 0; it < 8; it++) {
        int seg = (tid & 3) + it * 4;
        *(short8*)&lKV[row * 264 + seg * 8] = *(const short8*)(krow + seg * 8);
      }
    }
    __syncthreads();
#pragma unroll
    for (int ks = 0; ks < 8; ks++) {
#pragma unroll
      for (int nt = 0; nt < 4; nt++) {
        short8 bf = *(const short8*)&lKV[(nt * 16 + llo) * 264 + ks * 32 + lhi * 8];
        S[kc * 4 + nt] = __builtin_amdgcn_mfma_f32_16x16x32_bf16(qf[ks], bf, S[kc * 4 + nt], 0, 0, 0);
      }
    }
  }

  const int irow = i0 + wave * 16 + lhi * 4;
  float mx[4], sm[4];
#pragma unroll
  for (int r = 0; r < 4; r++) mx[r] = -3.0e38f;
#pragma unroll
  for (int st = 0; st < 12; st++) {
    int j = kw0 + st * 16 + llo;
#pragma unroll
    for (int r = 0; r < 4; r++) {
      int i = irow + r;
      bool ok = (j >= 0) & (j <= i) & (j >= i - WIN_);
      float s = ok ? S[st][r] : -1.0e30f;
      S[st][r] = s;
      mx[r] = fmaxf(mx[r], s);
    }
  }
#pragma unroll
  for (int r = 0; r < 4; r++)
#pragma unroll
    for (int o = 1; o < 16; o <<= 1) mx[r] = fmaxf(mx[r], __shfl_xor(mx[r], o));
#pragma unroll
  for (int r = 0; r < 4; r++) sm[r] = 0.f;
#pragma unroll
  for (int st = 0; st < 12; st++)
#pragma unroll
    for (int r = 0; r < 4; r++) {
      float e = __expf(S[st][r] - mx[r]);
      S[st][r] = e;
      sm[r] += e;
    }
#pragma unroll
  for (int r = 0; r < 4; r++) {
#pragma unroll
    for (int o = 1; o < 16; o <<= 1) sm[r] += __shfl_xor(sm[r], o);
    sm[r] = 1.f / sm[r];
  }

#pragma unroll
  for (int st = 0; st < 12; st++)
#pragma unroll
    for (int r = 0; r < 4; r++)
      lP[(wave * 16 + lhi * 4 + r) * 200 + st * 16 + llo] = f2bf(S[st][r] * sm[r]);

  f32x4 O[16];
#pragma unroll
  for (int nt = 0; nt < 16; nt++) O[nt] = f32x4{0.f, 0.f, 0.f, 0.f};

  for (int kc = 0; kc < 3; kc++) {
    __syncthreads();
#pragma unroll
    for (int it = 0; it < 8; it++) {
      int id = it * 256 + tid;
      int d = id >> 3, seg = id & 7;
      int kbase = min(max(kw0 + kc * 64 + seg * 8, 0), LTP_ - 8);
      *(short8*)&lKV[d * 72 + seg * 8] = *(const short8*)&vT[vbase + (size_t)d * LTP_ + kbase];
    }
    __syncthreads();
#pragma unroll
    for (int ks = 0; ks < 2; ks++) {
      short8 pf = *(const short8*)&lP[(wave * 16 + llo) * 200 + kc * 64 + ks * 32 + lhi * 8];
#pragma unroll
      for (int nt = 0; nt < 16; nt++) {
        short8 vf = *(const short8*)&lKV[(nt * 16 + llo) * 72 + ks * 32 + lhi * 8];
        O[nt] = __builtin_amdgcn_mfma_f32_16x16x32_bf16(pf, vf, O[nt], 0, 0, 0);
      }
    }
  }

  short* orow = outp + (size_t)(b * LT_) * D_ + h * HD_;
#pragma unroll
  for (int nt = 0; nt < 16; nt++)
#pragma unroll
    for (int r = 0; r < 4; r++) {
      int i = irow + r;
      if (i < LT_) orow[(size_t)i * D_ + nt * 16 + llo] = f2bf(O[nt][r]);
    }
}

// ---------------- fused double-LN: x1 = res + LN1(mo); xn = bf16(LN2(x1)) ----------------
__global__ __launch_bounds__(256, 4)
void ln2_kernel(const float* __restrict__ mo, const float* __restrict__ xres,
                const float* __restrict__ g1, const float* __restrict__ b1,
                const float* __restrict__ g2, const float* __restrict__ b2,
                float* __restrict__ x1, short* __restrict__ xn)
{
  const int row = blockIdx.x;
  const int tid = threadIdx.x;
  const int lane = tid & 63, wave = tid >> 6;
  __shared__ float red[8], red2[8];
  float4 v = ((const float4*)(mo + (size_t)row * D_))[tid];
  float s = v.x + v.y + v.z + v.w;
  float s2 = v.x * v.x + v.y * v.y + v.z * v.z + v.w * v.w;
#pragma unroll
  for (int o = 1; o < 64; o <<= 1) { s += __shfl_xor(s, o); s2 += __shfl_xor(s2, o); }
  if (lane == 0) { red[wave] = s; red[wave + 4] = s2; }
  __syncthreads();
  float S = red[0] + red[1] + red[2] + red[3];
  float S2 = red[4] + red[5] + red[6] + red[7];
  float mu = S * (1.f / D_);
  float rs = rsqrtf(S2 * (1.f / D_) - mu * mu + 1e-5f);
  float4 gg = ((const float4*)g1)[tid];
  float4 bb = ((const float4*)b1)[tid];
  float4 xv = ((const float4*)(xres + (size_t)row * D_))[tid];
  float4 o1;
  o1.x = xv.x + (v.x - mu) * rs * gg.x + bb.x;
  o1.y = xv.y + (v.y - mu) * rs * gg.y + bb.y;
  o1.z = xv.z + (v.z - mu) * rs * gg.z + bb.z;
  o1.w = xv.w + (v.w - mu) * rs * gg.w + bb.w;
  ((float4*)(x1 + (size_t)row * D_))[tid] = o1;
  s = o1.x + o1.y + o1.z + o1.w;
  s2 = o1.x * o1.x + o1.y * o1.y + o1.z * o1.z + o1.w * o1.w;
#pragma unroll
  for (int o = 1; o < 64; o <<= 1) { s += __shfl_xor(s, o); s2 += __shfl_xor(s2, o); }
  if (lane == 0) { red2[wave] = s; red2[wave + 4] = s2; }
  __syncthreads();
  S = red2[0] + red2[1] + red2[2] + red2[3];
  S2 = red2[4] + red2[5] + red2[6] + red2[7];
  float mu2 = S * (1.f / D_);
  float rs2 = rsqrtf(S2 * (1.f / D_) - mu2 * mu2 + 1e-5f);
  float4 g2v = ((const float4*)g2)[tid];
  float4 b2v = ((const float4*)b2)[tid];
  short o2[4];
  o2[0] = f2bf((o1.x - mu2) * rs2 * g2v.x + b2v.x);
  o2[1] = f2bf((o1.y - mu2) * rs2 * g2v.y + b2v.y);
  o2[2] = f2bf((o1.z - mu2) * rs2 * g2v.z + b2v.z);
  o2[3] = f2bf((o1.w - mu2) * rs2 * g2v.w + b2v.w);
  *(short4*)&xn[(size_t)row * D_ + tid * 4] = *(short4*)o2;
}

// ---------------- host launcher ----------------
extern "C" void kernel_launch(void* const* d_in, const int* in_sizes, int n_in,
                              void* d_out, int out_size, void* d_ws, size_t ws_size,
                              hipStream_t stream)
{
  const float* x      = (const float*)d_in[0];
  const float* cosp   = (const float*)d_in[1];
  const float* sinp   = (const float*)d_in[2];
  const float* go     = (const float*)d_in[3];
  const float* lo     = (const float*)d_in[4];
  const float* wq     = (const float*)d_in[5];
  const float* wk     = (const float*)d_in[6];
  const float* wv     = (const float*)d_in[7];
  const float* wo     = (const float*)d_in[8];
  const float* pmem   = (const float*)d_in[9];
  const float* gate_w = (const float*)d_in[10];
  const float* gate_b = (const float*)d_in[11];
  const float* outp_w = (const float*)d_in[12];
  const float* outp_b = (const float*)d_in[13];
  const float* ln1g   = (const float*)d_in[14];
  const float* ln1b   = (const float*)d_in[15];
  const float* ln2g   = (const float*)d_in[16];
  const float* ln2b   = (const float*)d_in[17];
  const float* fc1w   = (const float*)d_in[18];
  const float* fc1b   = (const float*)d_in[19];
  const float* fc2w   = (const float*)d_in[20];
  const float* fc2b   = (const float*)d_in[21];
  float* out = (float*)d_out;
  char* p = (char*)d_ws;

  // ---- workspace layout (~201.5 MB, lifetime-aliased) ----
  short* wqkvT = (short*)(p + 0);          //  6,291,456 (3072 x 1024 bf16: q|k|v)
  short* woT   = (short*)(p + 6291456);    //  2,097,152
  short* gateT = (short*)(p + 8388608);    // 18,874,368
  short* outpT = (short*)(p + 27262976);   //  6,291,456
  short* fc1T  = (short*)(p + 33554432);   //  8,388,608
  short* fc2T  = (short*)(p + 41943040);   //  8,388,608
  short* comb  = (short*)(p + 50331648);   // 50,331,648 (8192x3072 bf16)
  char*  pool  = p + 100663296;
  short* xp    = (short*)(pool);                   // 16,793,600 (8200x1024 bf16)
  short* qkv   = (short*)(pool + 16793600);        // 50,380,800 (8200x3072 bf16)
  short* vT    = (short*)(pool + 67174400);        // 16,842,752 (8 x 256 x 4112 bf16)
  short* a_o   = (short*)(pool + 84017152);        // 16,793,600
  // aliases (lifetimes disjoint):
  short* gated = (short*)(pool);                   // after core GEMM: over xp/qkv
  short* h1    = (short*)(pool);                   // after outproj: over xp..qkv
  float* mo    = (float*)(pool + 67174400);        // after attention: over vT+a_o
  float* x1    = (float*)(comb);                   // after gate GEMM: over comb
  short* xn    = (short*)((char*)comb + 33554432); // within old comb region

  // 1) all weight transposes in ONE launch
  TAll t;
  const float* srcs[8] = {wq, wk, wv, wo, gate_w, outp_w, fc1w, fc2w};
  short* dsts[8] = {wqkvT, wqkvT + 1048576, wqkvT + 2097152, woT, gateT, outpT, fc1T, fc2T};
  const int Rs[8] = {1024, 1024, 1024, 1024, 3072, 3072, 1024, 4096};
  const int Cs[8] = {1024, 1024, 1024, 1024, 3072, 1024, 4096, 1024};
  int cum = 0;
  for (int i = 0; i < 8; i++) {
    t.src[i] = srcs[i]; t.dst[i] = dsts[i];
    t.R[i] = Rs[i]; t.C[i] = Cs[i]; t.nbx[i] = Cs[i] / 32;
    t.start[i] = cum;
    cum += (Cs[i] / 32) * (Rs[i] / 32);
  }
  transpose_all<<<cum, 256, 0, stream>>>(t);   // cum = 24576

  // 2) xp = [pmem; x] bf16 ; combined[:, :2048]
  build_xp_k<<<8200, 256, 0, stream>>>(x, pmem, xp);
  combined01_k<<<16384, 256, 0, stream>>>(go, lo, comb);

  // 3) fused QKV projection (bf16 out, ldc=3072)
  const int Mq = B_ * LT_;   // 8200
  gemm_bt<EP_BF16, 128><<<dim3(65, 24), 256, 0, stream>>>(xp, 1024, wqkvT, qkv, QKL_, nullptr, nullptr, 0, Mq, 3072, 1024);

  // 4) RoPE in-place (q scaled by 1/16); V transposed to (B,H,HD,LTP)
  rope_kernel<<<4100, 256, 0, stream>>>(qkv, cosp, sinp);
  cast_transpose<short><<<dim3(8, 129, 8), 256, 0, stream>>>(
      qkv + 2048, vT, LT_, 256, QKL_, LTP_, 4,
      (size_t)LT_ * QKL_, 256, (size_t)4 * 256 * LTP_, (size_t)256 * LTP_);

  // 5) banded attention
  attn_kernel<<<dim3(65, H_, B_), 256, 0, stream>>>(qkv, vT, a_o);

  // 6) core_out = (attn @ wo) with pmem rows skipped -> combined[:, 2048:]
  gemm_bt<EP_CORE, 64><<<dim3(129, 8), 256, 0, stream>>>(
      a_o, 1024, woT, comb + 2048, 3072, nullptr, nullptr, 0, Mq, 1024, 1024);

  // 7) gated = combined * sigmoid(combined @ gate_w + gate_b)
  gemm_bt<EP_GATE, 128><<<dim3(64, 24), 256, 0, stream>>>(comb, 3072, gateT, gated, 3072, gate_b, comb, 3072, 8192, 3072, 3072);

  // 8) memory_output = gated @ outproj_w + b (f32)
  gemm_bt<EP_F32B, 64><<<dim3(128, 8), 256, 0, stream>>>(gated, 3072, outpT, mo, 1024, outp_b, nullptr, 0, 8192, 1024, 3072);

  // 9) x1 = x + LN1(mo); xn = bf16(LN2(x1))
  ln2_kernel<<<8192, 256, 0, stream>>>(mo, x, ln1g, ln1b, ln2g, ln2b, x1, xn);

  // 10) MLP: h1 = silu(xn @ fc1 + b1); out = x1 + h1 @ fc2 + b2
  gemm_bt<EP_SILU, 128><<<dim3(64, 32), 256, 0, stream>>>(xn, 1024, fc1T, h1, 4096, fc1b, nullptr, 0, 8192, 4096, 1024);
  gemm_bt<EP_RES, 64><<<dim3(128, 8), 256, 0, stream>>>(h1, 4096, fc2T, out, 1024, fc2b, x1, 1024, 8192, 1024, 4096);
}

// Round 4
// 972.184 us; speedup vs baseline: 1.0788x; 1.0788x over previous
//
#include <hip/hip_runtime.h>
#include <stdint.h>

// ---------------- problem constants ----------------
#define D_    1024
#define H_    4
#define HD_   256
#define WIN_  128
#define NPM_  4
#define B_    2
#define L_    4096
#define LT_   4100     // L + NPMEM
#define LTP_  4112     // padded row length for V^T (16B-aligned rows)
#define QKL_  3072     // fused qkv row stride

typedef __attribute__((ext_vector_type(8))) short short8;   // 8 bf16 (4 VGPRs)
typedef __attribute__((ext_vector_type(4))) float f32x4;    // MFMA acc

__device__ __forceinline__ short f2bf(float f) {
  union { float f; uint32_t u; } v; v.f = f;
  uint32_t r = v.u + 0x7FFFu + ((v.u >> 16) & 1u);   // RNE
  return (short)(r >> 16);
}
__device__ __forceinline__ float bf2f(short h) {
  union { uint32_t u; float f; } v; v.u = ((uint32_t)(uint16_t)h) << 16;
  return v.f;
}

// ---- async global->LDS (16B per lane; dest = wave-uniform base + lane*16) ----
typedef __attribute__((address_space(1))) void GAS;
typedef __attribute__((address_space(3))) void LAS;
__device__ __forceinline__ void gl16(const void* g, void* l) {
  __builtin_amdgcn_global_load_lds((GAS*)g, (LAS*)l, 16, 0, 0);
}
__device__ __forceinline__ void waitvm0() { asm volatile("s_waitcnt vmcnt(0)" ::: "memory"); }

// epilogue kinds
#define EP_BF16 0   // store bf16, no bias
#define EP_F32B 1   // store f32 + bias
#define EP_GATE 2   // g=sigmoid(acc+bias); store bf16( aux_bf16[r][c] * g )
#define EP_SILU 3   // v=acc+bias; store bf16( v*sigmoid(v) )
#define EP_RES  4   // store f32( acc + bias + aux_f32[r][c] )
#define EP_CORE 5   // store bf16, skipping pmem rows: row b*LT+t -> b*L+(t-NPM)

// ---------------- 128-tile GEMM: C(MxN) = A(MxK) * B^T(NxK), bf16 in, f32 acc ----
// m97-replica structure: 2 LDS buffers (32 KB total -> 3 blocks/CU TLP, the
// mechanism that hides the barrier drain, m114), global_load_lds width-16
// staging (gl16; +35% over reg-staged at this tile per m151), stage issued
// BEFORE the frag reads (T3 issue-early), one vmcnt(0)-drain + __syncthreads()
// per K-step. LDS dest is linear in tid (wave-uniform + lane*16); the
// zero-conflict XOR swizzle lives on the GLOBAL source side, so the staged
// byte layout is identical to the proven reg-staged path.
template<int EP, int TM>
__global__ __launch_bounds__(256, 2)
void gemm_bt(const short* __restrict__ A, int lda,
             const short* __restrict__ Bt,
             void* __restrict__ Cp, int ldc,
             const float* __restrict__ bias,
             const void* __restrict__ aux, int ldaux,
             int M, int N, int K)
{
  constexpr int WM = TM / 2;          // wave rows
  constexpr int MT = WM / 16;         // m-frags per wave
  constexpr int BUFSZ = (TM + 128) * 32;   // shorts per LDS buffer (A tile + B tile)
  __shared__ __attribute__((aligned(16))) short lds[2 * BUFSZ];
  const int tid  = threadIdx.x;
  const int lane = tid & 63, wave = tid >> 6;
  const int lhi  = lane >> 4, llo = lane & 15;
  const int m0 = blockIdx.x * TM, n0 = blockIdx.y * 128;
  const int mw = (wave >> 1) * WM, nw = (wave & 1) * 64;

  // staging: LDS row = tid>>2 (64B rows), phys seg = tid&3 holds global seg
  // (tid&3)^((tid>>3)&3); frag read recovers with lhi ^ ((llo>>1)&3).
  const int srow = tid >> 2;                       // 0..63
  const int sg   = (tid & 3) ^ ((tid >> 3) & 3);   // swizzled global 16B-seg
  const short* pA0 = A + (size_t)min(m0 + srow, M - 1) * lda + sg * 8;
  const short* pA1 = (TM == 128) ? A + (size_t)min(m0 + srow + 64, M - 1) * lda + sg * 8 : pA0;
  const short* pB0 = Bt + (size_t)(n0 + srow) * K + sg * 8;
  const short* pB1 = Bt + (size_t)(n0 + srow + 64) * K + sg * 8;

  const int segoff = (lhi ^ ((llo >> 1) & 3)) * 8;  // frag-read swizzle

  auto stage = [&](int b, int i) {
    const int k = i << 5;
    short* base = &lds[b * BUFSZ];
    gl16(pA0 + k, &base[tid * 8]);                          // A rows 0..63
    if constexpr (TM == 128) gl16(pA1 + k, &base[2048 + tid * 8]);  // A rows 64..127
    gl16(pB0 + k, &base[TM * 32 + tid * 8]);                // B rows 0..63
    gl16(pB1 + k, &base[TM * 32 + 2048 + tid * 8]);         // B rows 64..127
  };

  f32x4 acc[MT][4];
#pragma unroll
  for (int i = 0; i < MT; i++)
#pragma unroll
    for (int j = 0; j < 4; j++) acc[i][j] = f32x4{0.f, 0.f, 0.f, 0.f};

  const int NI = K >> 5;
  stage(0, 0);
  waitvm0();
  __syncthreads();

  for (int i = 0; i < NI; i++) {
    if (i + 1 < NI) stage((i + 1) & 1, i + 1);   // issue-early: loads fly over MFMA
    const short* bufp = &lds[(i & 1) * BUFSZ];
    short8 af[MT], bfr[4];
#pragma unroll
    for (int mt = 0; mt < MT; mt++)
      af[mt] = *(const short8*)&bufp[(mw + mt * 16 + llo) * 32 + segoff];
#pragma unroll
    for (int nt = 0; nt < 4; nt++)
      bfr[nt] = *(const short8*)&bufp[TM * 32 + (nw + nt * 16 + llo) * 32 + segoff];
#pragma unroll
    for (int mt = 0; mt < MT; mt++)
#pragma unroll
      for (int nt = 0; nt < 4; nt++)
        acc[mt][nt] = __builtin_amdgcn_mfma_f32_16x16x32_bf16(af[mt], bfr[nt], acc[mt][nt], 0, 0, 0);
    waitvm0();           // next buffer landed (drain covered by other blocks' waves)
    __syncthreads();     // + lgkm drain: all waves' reads of buf i complete
  }

  const int gcb = n0 + nw;
#pragma unroll
  for (int mt = 0; mt < MT; mt++) {
    const int gr0 = m0 + mw + mt * 16 + lhi * 4;
#pragma unroll
    for (int nt = 0; nt < 4; nt++) {
      const int gc = gcb + nt * 16 + llo;
      float bv = 0.f;
      if constexpr (EP != EP_BF16 && EP != EP_CORE) bv = bias[gc];
#pragma unroll
      for (int r = 0; r < 4; r++) {
        const int gr = gr0 + r;
        if (gr >= M) continue;
        const float v = acc[mt][nt][r];
        if constexpr (EP == EP_CORE) {
          const int b   = gr >= LT_ ? 1 : 0;
          const int tok = gr - b * LT_;
          if (tok >= NPM_) {
            const int cr = b * L_ + (tok - NPM_);
            ((short*)Cp)[(size_t)cr * ldc + gc] = f2bf(v);
          }
          continue;
        }
        const size_t idx = (size_t)gr * ldc + gc;
        if constexpr (EP == EP_BF16) {
          ((short*)Cp)[idx] = f2bf(v);
        } else if constexpr (EP == EP_F32B) {
          ((float*)Cp)[idx] = v + bv;
        } else if constexpr (EP == EP_GATE) {
          float g  = 1.f / (1.f + __expf(-(v + bv)));
          float cv = bf2f(((const short*)aux)[(size_t)gr * ldaux + gc]);
          ((short*)Cp)[idx] = f2bf(cv * g);
        } else if constexpr (EP == EP_SILU) {
          float xx = v + bv;
          ((short*)Cp)[idx] = f2bf(xx / (1.f + __expf(-xx)));
        } else {
          ((float*)Cp)[idx] = v + bv + ((const float*)aux)[(size_t)gr * ldaux + gc];
        }
      }
    }
  }
}

// ---------------- fused cast+transpose of ALL weights (one launch) ----------------
struct TAll {
  const float* src[8];
  short* dst[8];
  int C[8];     // src cols (ld_in)
  int R[8];     // src rows (ld_out)
  int nbx[8];   // C/32
  int start[8]; // cumulative block offsets
};

__global__ __launch_bounds__(256)
void transpose_all(TAll t)
{
  __shared__ short tile[32][33];
  const int bid = blockIdx.x;
  int w = 0;
#pragma unroll
  for (int i = 1; i < 8; i++) w = (bid >= t.start[i]) ? i : w;
  const int rel = bid - t.start[w];
  const int nbx = t.nbx[w];
  const int bx = rel % nbx, by = rel / nbx;
  const float* src = t.src[w];
  short* dst = t.dst[w];
  const int ld_in = t.C[w], ld_out = t.R[w];
  const int r0 = by * 32, c0 = bx * 32;
  const int tx = threadIdx.x & 31, ty = threadIdx.x >> 5;
#pragma unroll
  for (int i = 0; i < 4; i++)
    tile[ty + i * 8][tx] = f2bf(src[(size_t)(r0 + ty + i * 8) * ld_in + c0 + tx]);
  __syncthreads();
#pragma unroll
  for (int i = 0; i < 4; i++)
    dst[(size_t)(c0 + ty + i * 8) * ld_out + r0 + tx] = tile[tx][ty + i * 8];
}

// ---------------- cast + transpose (strided/z-batched; used for V^T) ----------------
template<typename Tin>
__global__ __launch_bounds__(256)
void cast_transpose(const Tin* __restrict__ in, short* __restrict__ outp,
                    int R, int C, int ld_in, int ld_out,
                    int zdiv, size_t inA, size_t inB, size_t outA, size_t outB)
{
  __shared__ short tile[32][33];
  const int z = blockIdx.z;
  const Tin* src = in + (size_t)(z / zdiv) * inA + (size_t)(z % zdiv) * inB;
  short* dst = outp + (size_t)(z / zdiv) * outA + (size_t)(z % zdiv) * outB;
  const int r0 = blockIdx.y * 32, c0 = blockIdx.x * 32;
  const int tx = threadIdx.x & 31, ty = threadIdx.x >> 5;
#pragma unroll
  for (int i = 0; i < 4; i++) {
    int r = r0 + ty + i * 8, c = c0 + tx;
    short v = 0;
    if (r < R && c < C) {
      if constexpr (sizeof(Tin) == 4) v = f2bf((float)src[(size_t)r * ld_in + c]);
      else                            v = (short)src[(size_t)r * ld_in + c];
    }
    tile[ty + i * 8][tx] = v;
  }
  __syncthreads();
#pragma unroll
  for (int i = 0; i < 4; i++) {
    int c = c0 + ty + i * 8, r = r0 + tx;
    if (c < C && r < R) dst[(size_t)c * ld_out + r] = tile[tx][ty + i * 8];
  }
}

// ---------------- build xp = [pmem ; x] cast to bf16, rows = B*Lt ----------------
__global__ __launch_bounds__(256)
void build_xp_k(const float* __restrict__ x, const float* __restrict__ pmem,
                short* __restrict__ xp)
{
  int gid = blockIdx.x * 256 + threadIdx.x;
  int row = gid >> 8;
  int c4  = (gid & 255) * 4;
  int b   = row >= LT_ ? 1 : 0;
  int tok = row - b * LT_;
  const float* src = (tok < NPM_) ? (pmem + (size_t)tok * D_ + c4)
                                  : (x + ((size_t)b * L_ + tok - NPM_) * D_ + c4);
  float4 v = *(const float4*)src;
  short o[4] = {f2bf(v.x), f2bf(v.y), f2bf(v.z), f2bf(v.w)};
  *(short4*)&xp[(size_t)row * D_ + c4] = *(short4*)o;
}

// ---------------- combined[:, 0:2048] = cast(global_out | local_out) ----------------
__global__ __launch_bounds__(256)
void combined01_k(const float* __restrict__ go, const float* __restrict__ lo,
                  short* __restrict__ comb)
{
  int gid = blockIdx.x * 256 + threadIdx.x;
  int row = gid >> 9;
  int c4  = (gid & 511) * 4;
  const float* src = (c4 < D_) ? (go + (size_t)row * D_ + c4)
                               : (lo + (size_t)row * D_ + (c4 - D_));
  float4 v = *(const float4*)src;
  short o[4] = {f2bf(v.x), f2bf(v.y), f2bf(v.z), f2bf(v.w)};
  *(short4*)&comb[(size_t)row * 3072 + c4] = *(short4*)o;
}

// ---------------- in-place RoPE on fused qkv (bf16); folds 1/sqrt(HD) into q ----------------
__global__ __launch_bounds__(256)
void rope_kernel(short* __restrict__ qkv,
                 const float* __restrict__ cosp, const float* __restrict__ sinp)
{
  int gid = blockIdx.x * 256 + threadIdx.x;       // 8200 rows * 4 heads * 32 quads; exact
  int d   = (gid & 31) * 4;
  int h   = (gid >> 5) & 3;
  int row = gid >> 7;
  int t   = row >= LT_ ? row - LT_ : row;
  size_t base = (size_t)row * QKL_ + h * HD_ + d;
  float4 cl = *(const float4*)&cosp[(size_t)t * HD_ + d];
  float4 ch = *(const float4*)&cosp[(size_t)t * HD_ + d + 128];
  float4 sl = *(const float4*)&sinp[(size_t)t * HD_ + d];
  float4 sh = *(const float4*)&sinp[(size_t)t * HD_ + d + 128];
  short4 ql4 = *(const short4*)&qkv[base],        qh4 = *(const short4*)&qkv[base + 128];
  short4 kl4 = *(const short4*)&qkv[base + 1024], kh4 = *(const short4*)&qkv[base + 1152];
  const float SC = 1.f / 16.f;   // 1/sqrt(256)
  short oql[4], oqh[4], okl[4], okh[4];
#pragma unroll
  for (int j = 0; j < 4; j++) {
    float c0 = ((float*)&cl)[j], c1 = ((float*)&ch)[j];
    float s0 = ((float*)&sl)[j], s1 = ((float*)&sh)[j];
    float ql = bf2f(((short*)&ql4)[j]), qh = bf2f(((short*)&qh4)[j]);
    float kl = bf2f(((short*)&kl4)[j]), kh = bf2f(((short*)&kh4)[j]);
    oql[j] = f2bf((ql * c0 - qh * s0) * SC);
    oqh[j] = f2bf((qh * c1 + ql * s1) * SC);
    okl[j] = f2bf(kl * c0 - kh * s0);
    okh[j] = f2bf(kh * c1 + kl * s1);
  }
  *(short4*)&qkv[base]        = *(short4*)oql;
  *(short4*)&qkv[base + 128]  = *(short4*)oqh;
  *(short4*)&qkv[base + 1024] = *(short4*)okl;
  *(short4*)&qkv[base + 1152] = *(short4*)okh;
}

// ---------------- banded attention, MFMA; 64 queries/block, 192-key window ----------------
__global__ __launch_bounds__(256, 1)
void attn_kernel(const short* __restrict__ qkv, const short* __restrict__ vT,
                 short* __restrict__ outp)
{
  __shared__ short lKV[256 * 72];   // K chunk (64x264) or V^T chunk (256x72)
  __shared__ short lP[64 * 200];    // P: 64 q-rows x 192 keys (+pad)
  const int tid  = threadIdx.x;
  const int lane = tid & 63, wave = tid >> 6;
  const int lhi  = lane >> 4, llo = lane & 15;
  const int i0 = blockIdx.x * 64;
  const int h = blockIdx.y, b = blockIdx.z;
  const int kw0 = i0 - 128;
  const size_t vbase = (size_t)(b * H_ + h) * HD_ * LTP_;

  short8 qf[8];
  {
    int ic = min(i0 + wave * 16 + llo, LT_ - 1);
    const short* qrow = qkv + (size_t)(b * LT_ + ic) * QKL_ + h * HD_;
#pragma unroll
    for (int ks = 0; ks < 8; ks++)
      qf[ks] = *(const short8*)(qrow + ks * 32 + lhi * 8);
  }

  f32x4 S[12];
#pragma unroll
  for (int st = 0; st < 12; st++) S[st] = f32x4{0.f, 0.f, 0.f, 0.f};

  for (int kc = 0; kc < 3; kc++) {
    if (kc) __syncthreads();
    {
      int row = tid >> 2;
      int jc = min(max(kw0 + kc * 64 + row, 0), LT_ - 1);
      const short* krow = qkv + (size_t)(b * LT_ + jc) * QKL_ + 1024 + h * HD_;
#pragma unroll
      for (int it = 0; it < 8; it++) {
        int seg = (tid & 3) + it * 4;
        *(short8*)&lKV[row * 264 + seg * 8] = *(const short8*)(krow + seg * 8);
      }
    }
    __syncthreads();
#pragma unroll
    for (int ks = 0; ks < 8; ks++) {
#pragma unroll
      for (int nt = 0; nt < 4; nt++) {
        short8 bf = *(const short8*)&lKV[(nt * 16 + llo) * 264 + ks * 32 + lhi * 8];
        S[kc * 4 + nt] = __builtin_amdgcn_mfma_f32_16x16x32_bf16(qf[ks], bf, S[kc * 4 + nt], 0, 0, 0);
      }
    }
  }

  const int irow = i0 + wave * 16 + lhi * 4;
  float mx[4], sm[4];
#pragma unroll
  for (int r = 0; r < 4; r++) mx[r] = -3.0e38f;
#pragma unroll
  for (int st = 0; st < 12; st++) {
    int j = kw0 + st * 16 + llo;
#pragma unroll
    for (int r = 0; r < 4; r++) {
      int i = irow + r;
      bool ok = (j >= 0) & (j <= i) & (j >= i - WIN_);
      float s = ok ? S[st][r] : -1.0e30f;
      S[st][r] = s;
      mx[r] = fmaxf(mx[r], s);
    }
  }
#pragma unroll
  for (int r = 0; r < 4; r++)
#pragma unroll
    for (int o = 1; o < 16; o <<= 1) mx[r] = fmaxf(mx[r], __shfl_xor(mx[r], o));
#pragma unroll
  for (int r = 0; r < 4; r++) sm[r] = 0.f;
#pragma unroll
  for (int st = 0; st < 12; st++)
#pragma unroll
    for (int r = 0; r < 4; r++) {
      float e = __expf(S[st][r] - mx[r]);
      S[st][r] = e;
      sm[r] += e;
    }
#pragma unroll
  for (int r = 0; r < 4; r++) {
#pragma unroll
    for (int o = 1; o < 16; o <<= 1) sm[r] += __shfl_xor(sm[r], o);
    sm[r] = 1.f / sm[r];
  }

#pragma unroll
  for (int st = 0; st < 12; st++)
#pragma unroll
    for (int r = 0; r < 4; r++)
      lP[(wave * 16 + lhi * 4 + r) * 200 + st * 16 + llo] = f2bf(S[st][r] * sm[r]);

  f32x4 O[16];
#pragma unroll
  for (int nt = 0; nt < 16; nt++) O[nt] = f32x4{0.f, 0.f, 0.f, 0.f};

  for (int kc = 0; kc < 3; kc++) {
    __syncthreads();
#pragma unroll
    for (int it = 0; it < 8; it++) {
      int id = it * 256 + tid;
      int d = id >> 3, seg = id & 7;
      int kbase = min(max(kw0 + kc * 64 + seg * 8, 0), LTP_ - 8);
      *(short8*)&lKV[d * 72 + seg * 8] = *(const short8*)&vT[vbase + (size_t)d * LTP_ + kbase];
    }
    __syncthreads();
#pragma unroll
    for (int ks = 0; ks < 2; ks++) {
      short8 pf = *(const short8*)&lP[(wave * 16 + llo) * 200 + kc * 64 + ks * 32 + lhi * 8];
#pragma unroll
      for (int nt = 0; nt < 16; nt++) {
        short8 vf = *(const short8*)&lKV[(nt * 16 + llo) * 72 + ks * 32 + lhi * 8];
        O[nt] = __builtin_amdgcn_mfma_f32_16x16x32_bf16(pf, vf, O[nt], 0, 0, 0);
      }
    }
  }

  short* orow = outp + (size_t)(b * LT_) * D_ + h * HD_;
#pragma unroll
  for (int nt = 0; nt < 16; nt++)
#pragma unroll
    for (int r = 0; r < 4; r++) {
      int i = irow + r;
      if (i < LT_) orow[(size_t)i * D_ + nt * 16 + llo] = f2bf(O[nt][r]);
    }
}

// ---------------- fused double-LN: x1 = res + LN1(mo); xn = bf16(LN2(x1)) ----------------
__global__ __launch_bounds__(256, 4)
void ln2_kernel(const float* __restrict__ mo, const float* __restrict__ xres,
                const float* __restrict__ g1, const float* __restrict__ b1,
                const float* __restrict__ g2, const float* __restrict__ b2,
                float* __restrict__ x1, short* __restrict__ xn)
{
  const int row = blockIdx.x;
  const int tid = threadIdx.x;
  const int lane = tid & 63, wave = tid >> 6;
  __shared__ float red[8], red2[8];
  float4 v = ((const float4*)(mo + (size_t)row * D_))[tid];
  float s = v.x + v.y + v.z + v.w;
  float s2 = v.x * v.x + v.y * v.y + v.z * v.z + v.w * v.w;
#pragma unroll
  for (int o = 1; o < 64; o <<= 1) { s += __shfl_xor(s, o); s2 += __shfl_xor(s2, o); }
  if (lane == 0) { red[wave] = s; red[wave + 4] = s2; }
  __syncthreads();
  float S = red[0] + red[1] + red[2] + red[3];
  float S2 = red[4] + red[5] + red[6] + red[7];
  float mu = S * (1.f / D_);
  float rs = rsqrtf(S2 * (1.f / D_) - mu * mu + 1e-5f);
  float4 gg = ((const float4*)g1)[tid];
  float4 bb = ((const float4*)b1)[tid];
  float4 xv = ((const float4*)(xres + (size_t)row * D_))[tid];
  float4 o1;
  o1.x = xv.x + (v.x - mu) * rs * gg.x + bb.x;
  o1.y = xv.y + (v.y - mu) * rs * gg.y + bb.y;
  o1.z = xv.z + (v.z - mu) * rs * gg.z + bb.z;
  o1.w = xv.w + (v.w - mu) * rs * gg.w + bb.w;
  ((float4*)(x1 + (size_t)row * D_))[tid] = o1;
  s = o1.x + o1.y + o1.z + o1.w;
  s2 = o1.x * o1.x + o1.y * o1.y + o1.z * o1.z + o1.w * o1.w;
#pragma unroll
  for (int o = 1; o < 64; o <<= 1) { s += __shfl_xor(s, o); s2 += __shfl_xor(s2, o); }
  if (lane == 0) { red2[wave] = s; red2[wave + 4] = s2; }
  __syncthreads();
  S = red2[0] + red2[1] + red2[2] + red2[3];
  S2 = red2[4] + red2[5] + red2[6] + red2[7];
  float mu2 = S * (1.f / D_);
  float rs2 = rsqrtf(S2 * (1.f / D_) - mu2 * mu2 + 1e-5f);
  float4 g2v = ((const float4*)g2)[tid];
  float4 b2v = ((const float4*)b2)[tid];
  short o2[4];
  o2[0] = f2bf((o1.x - mu2) * rs2 * g2v.x + b2v.x);
  o2[1] = f2bf((o1.y - mu2) * rs2 * g2v.y + b2v.y);
  o2[2] = f2bf((o1.z - mu2) * rs2 * g2v.z + b2v.z);
  o2[3] = f2bf((o1.w - mu2) * rs2 * g2v.w + b2v.w);
  *(short4*)&xn[(size_t)row * D_ + tid * 4] = *(short4*)o2;
}

// ---------------- host launcher ----------------
extern "C" void kernel_launch(void* const* d_in, const int* in_sizes, int n_in,
                              void* d_out, int out_size, void* d_ws, size_t ws_size,
                              hipStream_t stream)
{
  const float* x      = (const float*)d_in[0];
  const float* cosp   = (const float*)d_in[1];
  const float* sinp   = (const float*)d_in[2];
  const float* go     = (const float*)d_in[3];
  const float* lo     = (const float*)d_in[4];
  const float* wq     = (const float*)d_in[5];
  const float* wk     = (const float*)d_in[6];
  const float* wv     = (const float*)d_in[7];
  const float* wo     = (const float*)d_in[8];
  const float* pmem   = (const float*)d_in[9];
  const float* gate_w = (const float*)d_in[10];
  const float* gate_b = (const float*)d_in[11];
  const float* outp_w = (const float*)d_in[12];
  const float* outp_b = (const float*)d_in[13];
  const float* ln1g   = (const float*)d_in[14];
  const float* ln1b   = (const float*)d_in[15];
  const float* ln2g   = (const float*)d_in[16];
  const float* ln2b   = (const float*)d_in[17];
  const float* fc1w   = (const float*)d_in[18];
  const float* fc1b   = (const float*)d_in[19];
  const float* fc2w   = (const float*)d_in[20];
  const float* fc2b   = (const float*)d_in[21];
  float* out = (float*)d_out;
  char* p = (char*)d_ws;

  // ---- workspace layout (~201.5 MB, lifetime-aliased) ----
  short* wqkvT = (short*)(p + 0);          //  6,291,456 (3072 x 1024 bf16: q|k|v)
  short* woT   = (short*)(p + 6291456);    //  2,097,152
  short* gateT = (short*)(p + 8388608);    // 18,874,368
  short* outpT = (short*)(p + 27262976);   //  6,291,456
  short* fc1T  = (short*)(p + 33554432);   //  8,388,608
  short* fc2T  = (short*)(p + 41943040);   //  8,388,608
  short* comb  = (short*)(p + 50331648);   // 50,331,648 (8192x3072 bf16)
  char*  pool  = p + 100663296;
  short* xp    = (short*)(pool);                   // 16,793,600 (8200x1024 bf16)
  short* qkv   = (short*)(pool + 16793600);        // 50,380,800 (8200x3072 bf16)
  short* vT    = (short*)(pool + 67174400);        // 16,842,752 (8 x 256 x 4112 bf16)
  short* a_o   = (short*)(pool + 84017152);        // 16,793,600
  // aliases (lifetimes disjoint):
  short* gated = (short*)(pool);                   // after core GEMM: over xp/qkv
  short* h1    = (short*)(pool);                   // after outproj: over xp..qkv
  float* mo    = (float*)(pool + 67174400);        // after attention: over vT+a_o
  float* x1    = (float*)(comb);                   // after gate GEMM: over comb
  short* xn    = (short*)((char*)comb + 33554432); // within old comb region

  // 1) all weight transposes in ONE launch
  TAll t;
  const float* srcs[8] = {wq, wk, wv, wo, gate_w, outp_w, fc1w, fc2w};
  short* dsts[8] = {wqkvT, wqkvT + 1048576, wqkvT + 2097152, woT, gateT, outpT, fc1T, fc2T};
  const int Rs[8] = {1024, 1024, 1024, 1024, 3072, 3072, 1024, 4096};
  const int Cs[8] = {1024, 1024, 1024, 1024, 3072, 1024, 4096, 1024};
  int cum = 0;
  for (int i = 0; i < 8; i++) {
    t.src[i] = srcs[i]; t.dst[i] = dsts[i];
    t.R[i] = Rs[i]; t.C[i] = Cs[i]; t.nbx[i] = Cs[i] / 32;
    t.start[i] = cum;
    cum += (Cs[i] / 32) * (Rs[i] / 32);
  }
  transpose_all<<<cum, 256, 0, stream>>>(t);   // cum = 24576

  // 2) xp = [pmem; x] bf16 ; combined[:, :2048]
  build_xp_k<<<8200, 256, 0, stream>>>(x, pmem, xp);
  combined01_k<<<16384, 256, 0, stream>>>(go, lo, comb);

  // 3) fused QKV projection (bf16 out, ldc=3072)
  const int Mq = B_ * LT_;   // 8200
  gemm_bt<EP_BF16, 128><<<dim3(65, 24), 256, 0, stream>>>(xp, 1024, wqkvT, qkv, QKL_, nullptr, nullptr, 0, Mq, 3072, 1024);

  // 4) RoPE in-place (q scaled by 1/16); V transposed to (B,H,HD,LTP)
  rope_kernel<<<4100, 256, 0, stream>>>(qkv, cosp, sinp);
  cast_transpose<short><<<dim3(8, 129, 8), 256, 0, stream>>>(
      qkv + 2048, vT, LT_, 256, QKL_, LTP_, 4,
      (size_t)LT_ * QKL_, 256, (size_t)4 * 256 * LTP_, (size_t)256 * LTP_);

  // 5) banded attention
  attn_kernel<<<dim3(65, H_, B_), 256, 0, stream>>>(qkv, vT, a_o);

  // 6) core_out = (attn @ wo) with pmem rows skipped -> combined[:, 2048:]
  gemm_bt<EP_CORE, 64><<<dim3(129, 8), 256, 0, stream>>>(
      a_o, 1024, woT, comb + 2048, 3072, nullptr, nullptr, 0, Mq, 1024, 1024);

  // 7) gated = combined * sigmoid(combined @ gate_w + gate_b)
  gemm_bt<EP_GATE, 128><<<dim3(64, 24), 256, 0, stream>>>(comb, 3072, gateT, gated, 3072, gate_b, comb, 3072, 8192, 3072, 3072);

  // 8) memory_output = gated @ outproj_w + b (f32)
  gemm_bt<EP_F32B, 64><<<dim3(128, 8), 256, 0, stream>>>(gated, 3072, outpT, mo, 1024, outp_b, nullptr, 0, 8192, 1024, 3072);

  // 9) x1 = x + LN1(mo); xn = bf16(LN2(x1))
  ln2_kernel<<<8192, 256, 0, stream>>>(mo, x, ln1g, ln1b, ln2g, ln2b, x1, xn);

  // 10) MLP: h1 = silu(xn @ fc1 + b1); out = x1 + h1 @ fc2 + b2
  gemm_bt<EP_SILU, 128><<<dim3(64, 32), 256, 0, stream>>>(xn, 1024, fc1T, h1, 4096, fc1b, nullptr, 0, 8192, 4096, 1024);
  gemm_bt<EP_RES, 64><<<dim3(128, 8), 256, 0, stream>>>(h1, 4096, fc2T, out, 1024, fc2b, x1, 1024, 8192, 1024, 4096);
}

// Round 5
// 969.063 us; speedup vs baseline: 1.0823x; 1.0032x over previous
//
#include <hip/hip_runtime.h>
#include <stdint.h>

// ---------------- problem constants ----------------
#define D_    1024
#define H_    4
#define HD_   256
#define WIN_  128
#define NPM_  4
#define B_    2
#define L_    4096
#define LT_   4100     // L + NPMEM
#define LTP_  4112     // padded row length for V^T (16B-aligned rows)
#define QKL_  2048     // fused qk row stride (v is produced directly as V^T)

typedef __attribute__((ext_vector_type(8))) short short8;   // 8 bf16 (4 VGPRs)
typedef __attribute__((ext_vector_type(4))) float f32x4;    // MFMA acc

__device__ __forceinline__ short f2bf(float f) {
  union { float f; uint32_t u; } v; v.f = f;
  uint32_t r = v.u + 0x7FFFu + ((v.u >> 16) & 1u);   // RNE
  return (short)(r >> 16);
}
__device__ __forceinline__ float bf2f(short h) {
  union { uint32_t u; float f; } v; v.u = ((uint32_t)(uint16_t)h) << 16;
  return v.f;
}

// ---- async global->LDS (16B per lane; dest = wave-uniform base + lane*16) ----
typedef __attribute__((address_space(1))) void GAS;
typedef __attribute__((address_space(3))) void LAS;
__device__ __forceinline__ void gl16(const void* g, void* l) {
  __builtin_amdgcn_global_load_lds((GAS*)g, (LAS*)l, 16, 0, 0);
}
__device__ __forceinline__ void waitvm0() { asm volatile("s_waitcnt vmcnt(0)" ::: "memory"); }

// epilogue kinds
#define EP_BF16 0   // store bf16, no bias
#define EP_F32B 1   // store f32 + bias
#define EP_GATE 2   // g=sigmoid(acc+bias); store bf16( aux_bf16[r][c] * g )
#define EP_SILU 3   // v=acc+bias; store bf16( v*sigmoid(v) )
#define EP_RES  4   // store f32( acc + bias + aux_f32[r][c] )
#define EP_CORE 5   // store bf16, skipping pmem rows: row b*LT+t -> b*L+(t-NPM)
#define EP_VT   6   // V^T producer: row gr=(h*256+dd), col gc=token -> vT[(b,h,dd,tok)]

// ---------------- 128-tile GEMM: C(MxN) = A(MxK) * B^T(NxK), bf16 in, f32 acc ----
// m97-replica: 2 LDS buffers (32 KB -> 3-4 blocks/CU TLP), global_load_lds
// width-16 staging, stage issued before frag reads, vmcnt(0)+__syncthreads per
// K-step. Zero-conflict XOR swizzle applied on the GLOBAL source side; LDS dest
// linear in tid. (256,4): VGPR+AGPR ~120 <= 128 budget -> 4 blocks/CU legal.
template<int EP, int TM>
__global__ __launch_bounds__(256, 4)
void gemm_bt(const short* __restrict__ A, int lda,
             const short* __restrict__ Bt,
             void* __restrict__ Cp, int ldc,
             const float* __restrict__ bias,
             const void* __restrict__ aux, int ldaux,
             int M, int N, int K)
{
  constexpr int WM = TM / 2;          // wave rows
  constexpr int MT = WM / 16;         // m-frags per wave
  constexpr int BUFSZ = (TM + 128) * 32;   // shorts per LDS buffer (A tile + B tile)
  __shared__ __attribute__((aligned(16))) short lds[2 * BUFSZ];
  const int tid  = threadIdx.x;
  const int lane = tid & 63, wave = tid >> 6;
  const int lhi  = lane >> 4, llo = lane & 15;
  const int m0 = blockIdx.x * TM, n0 = blockIdx.y * 128;
  const int mw = (wave >> 1) * WM, nw = (wave & 1) * 64;

  // staging: LDS row = tid>>2 (64B rows), phys seg = tid&3 holds global seg
  // (tid&3)^((tid>>3)&3); frag read recovers with lhi ^ ((llo>>1)&3).
  const int srow = tid >> 2;                       // 0..63
  const int sg   = (tid & 3) ^ ((tid >> 3) & 3);   // swizzled global 16B-seg
  const short* pA0 = A + (size_t)min(m0 + srow, M - 1) * lda + sg * 8;
  const short* pA1 = (TM == 128) ? A + (size_t)min(m0 + srow + 64, M - 1) * lda + sg * 8 : pA0;
  // NOTE (EP_VT): B rows may run past N up to the 128-pad; callers guarantee the
  // overrun stays inside the workspace (reads are garbage, masked at write).
  const short* pB0 = Bt + (size_t)(n0 + srow) * K + sg * 8;
  const short* pB1 = Bt + (size_t)(n0 + srow + 64) * K + sg * 8;

  const int segoff = (lhi ^ ((llo >> 1) & 3)) * 8;  // frag-read swizzle

  auto stage = [&](int b, int i) {
    const int k = i << 5;
    short* base = &lds[b * BUFSZ];
    gl16(pA0 + k, &base[tid * 8]);                          // A rows 0..63
    if constexpr (TM == 128) gl16(pA1 + k, &base[2048 + tid * 8]);  // A rows 64..127
    gl16(pB0 + k, &base[TM * 32 + tid * 8]);                // B rows 0..63
    gl16(pB1 + k, &base[TM * 32 + 2048 + tid * 8]);         // B rows 64..127
  };

  f32x4 acc[MT][4];
#pragma unroll
  for (int i = 0; i < MT; i++)
#pragma unroll
    for (int j = 0; j < 4; j++) acc[i][j] = f32x4{0.f, 0.f, 0.f, 0.f};

  const int NI = K >> 5;
  stage(0, 0);
  waitvm0();
  __syncthreads();

  for (int i = 0; i < NI; i++) {
    if (i + 1 < NI) stage((i + 1) & 1, i + 1);   // issue-early: loads fly over MFMA
    const short* bufp = &lds[(i & 1) * BUFSZ];
    short8 af[MT], bfr[4];
#pragma unroll
    for (int mt = 0; mt < MT; mt++)
      af[mt] = *(const short8*)&bufp[(mw + mt * 16 + llo) * 32 + segoff];
#pragma unroll
    for (int nt = 0; nt < 4; nt++)
      bfr[nt] = *(const short8*)&bufp[TM * 32 + (nw + nt * 16 + llo) * 32 + segoff];
#pragma unroll
    for (int mt = 0; mt < MT; mt++)
#pragma unroll
      for (int nt = 0; nt < 4; nt++)
        acc[mt][nt] = __builtin_amdgcn_mfma_f32_16x16x32_bf16(af[mt], bfr[nt], acc[mt][nt], 0, 0, 0);
    waitvm0();           // next buffer landed (drain covered by other blocks' waves)
    __syncthreads();     // + lgkm drain: all waves' reads of buf i complete
  }

  const int gcb = n0 + nw;
#pragma unroll
  for (int mt = 0; mt < MT; mt++) {
    const int gr0 = m0 + mw + mt * 16 + lhi * 4;
#pragma unroll
    for (int nt = 0; nt < 4; nt++) {
      const int gc = gcb + nt * 16 + llo;
      float bv = 0.f;
      if constexpr (EP != EP_BF16 && EP != EP_CORE && EP != EP_VT) bv = bias[gc];
#pragma unroll
      for (int r = 0; r < 4; r++) {
        const int gr = gr0 + r;
        if (gr >= M) continue;
        const float v = acc[mt][nt][r];
        if constexpr (EP == EP_VT) {
          // gr = h*256+dd (M=1024), gc = global token col (N=8200, 128-padded)
          if (gc < N) {
            const int b   = gc >= LT_ ? 1 : 0;
            const int tok = gc - b * LT_;
            const int hh  = gr >> 8, dd = gr & 255;
            ((short*)Cp)[(size_t)((b * H_ + hh) * HD_ + dd) * ldc + tok] = f2bf(v);
          }
          continue;
        }
        if constexpr (EP == EP_CORE) {
          const int b   = gr >= LT_ ? 1 : 0;
          const int tok = gr - b * LT_;
          if (tok >= NPM_) {
            const int cr = b * L_ + (tok - NPM_);
            ((short*)Cp)[(size_t)cr * ldc + gc] = f2bf(v);
          }
          continue;
        }
        const size_t idx = (size_t)gr * ldc + gc;
        if constexpr (EP == EP_BF16) {
          ((short*)Cp)[idx] = f2bf(v);
        } else if constexpr (EP == EP_F32B) {
          ((float*)Cp)[idx] = v + bv;
        } else if constexpr (EP == EP_GATE) {
          float g  = 1.f / (1.f + __expf(-(v + bv)));
          float cv = bf2f(((const short*)aux)[(size_t)gr * ldaux + gc]);
          ((short*)Cp)[idx] = f2bf(cv * g);
        } else if constexpr (EP == EP_SILU) {
          float xx = v + bv;
          ((short*)Cp)[idx] = f2bf(xx / (1.f + __expf(-xx)));
        } else {
          ((float*)Cp)[idx] = v + bv + ((const float*)aux)[(size_t)gr * ldaux + gc];
        }
      }
    }
  }
}

// ---------------- fused cast+transpose of ALL weights (one launch) ----------------
struct TAll {
  const float* src[8];
  short* dst[8];
  int C[8];     // src cols (ld_in)
  int R[8];     // src rows (ld_out)
  int nbx[8];   // C/32
  int start[8]; // cumulative block offsets
};

__global__ __launch_bounds__(256)
void transpose_all(TAll t)
{
  __shared__ short tile[32][33];
  const int bid = blockIdx.x;
  int w = 0;
#pragma unroll
  for (int i = 1; i < 8; i++) w = (bid >= t.start[i]) ? i : w;
  const int rel = bid - t.start[w];
  const int nbx = t.nbx[w];
  const int bx = rel % nbx, by = rel / nbx;
  const float* src = t.src[w];
  short* dst = t.dst[w];
  const int ld_in = t.C[w], ld_out = t.R[w];
  const int r0 = by * 32, c0 = bx * 32;
  const int tx = threadIdx.x & 31, ty = threadIdx.x >> 5;
#pragma unroll
  for (int i = 0; i < 4; i++)
    tile[ty + i * 8][tx] = f2bf(src[(size_t)(r0 + ty + i * 8) * ld_in + c0 + tx]);
  __syncthreads();
#pragma unroll
  for (int i = 0; i < 4; i++)
    dst[(size_t)(c0 + ty + i * 8) * ld_out + r0 + tx] = tile[tx][ty + i * 8];
}

// ---------------- fused prep: xp = [pmem;x] bf16  AND  combined[:, :2048] ----------------
// blocks 0..8199: xp rows; blocks 8200..24583: comb rows.
__global__ __launch_bounds__(256)
void prep_k(const float* __restrict__ x, const float* __restrict__ pmem,
            const float* __restrict__ go, const float* __restrict__ lo,
            short* __restrict__ xp, short* __restrict__ comb)
{
  const int bid = blockIdx.x;
  if (bid < 8200) {
    int gid = bid * 256 + threadIdx.x;
    int row = gid >> 8;
    int c4  = (gid & 255) * 4;
    int b   = row >= LT_ ? 1 : 0;
    int tok = row - b * LT_;
    const float* src = (tok < NPM_) ? (pmem + (size_t)tok * D_ + c4)
                                    : (x + ((size_t)b * L_ + tok - NPM_) * D_ + c4);
    float4 v = *(const float4*)src;
    short o[4] = {f2bf(v.x), f2bf(v.y), f2bf(v.z), f2bf(v.w)};
    *(short4*)&xp[(size_t)row * D_ + c4] = *(short4*)o;
  } else {
    int gid = (bid - 8200) * 256 + threadIdx.x;
    int row = gid >> 9;
    int c4  = (gid & 511) * 4;
    const float* src = (c4 < D_) ? (go + (size_t)row * D_ + c4)
                                 : (lo + (size_t)row * D_ + (c4 - D_));
    float4 v = *(const float4*)src;
    short o[4] = {f2bf(v.x), f2bf(v.y), f2bf(v.z), f2bf(v.w)};
    *(short4*)&comb[(size_t)row * 3072 + c4] = *(short4*)o;
  }
}

// ---------------- in-place RoPE on fused qk (bf16); folds 1/sqrt(HD) into q ----------------
__global__ __launch_bounds__(256)
void rope_kernel(short* __restrict__ qkv,
                 const float* __restrict__ cosp, const float* __restrict__ sinp)
{
  int gid = blockIdx.x * 256 + threadIdx.x;       // 8200 rows * 4 heads * 32 quads; exact
  int d   = (gid & 31) * 4;
  int h   = (gid >> 5) & 3;
  int row = gid >> 7;
  int t   = row >= LT_ ? row - LT_ : row;
  size_t base = (size_t)row * QKL_ + h * HD_ + d;
  float4 cl = *(const float4*)&cosp[(size_t)t * HD_ + d];
  float4 ch = *(const float4*)&cosp[(size_t)t * HD_ + d + 128];
  float4 sl = *(const float4*)&sinp[(size_t)t * HD_ + d];
  float4 sh = *(const float4*)&sinp[(size_t)t * HD_ + d + 128];
  short4 ql4 = *(const short4*)&qkv[base],        qh4 = *(const short4*)&qkv[base + 128];
  short4 kl4 = *(const short4*)&qkv[base + 1024], kh4 = *(const short4*)&qkv[base + 1152];
  const float SC = 1.f / 16.f;   // 1/sqrt(256)
  short oql[4], oqh[4], okl[4], okh[4];
#pragma unroll
  for (int j = 0; j < 4; j++) {
    float c0 = ((float*)&cl)[j], c1 = ((float*)&ch)[j];
    float s0 = ((float*)&sl)[j], s1 = ((float*)&sh)[j];
    float ql = bf2f(((short*)&ql4)[j]), qh = bf2f(((short*)&qh4)[j]);
    float kl = bf2f(((short*)&kl4)[j]), kh = bf2f(((short*)&kh4)[j]);
    oql[j] = f2bf((ql * c0 - qh * s0) * SC);
    oqh[j] = f2bf((qh * c1 + ql * s1) * SC);
    okl[j] = f2bf(kl * c0 - kh * s0);
    okh[j] = f2bf(kh * c1 + kl * s1);
  }
  *(short4*)&qkv[base]        = *(short4*)oql;
  *(short4*)&qkv[base + 128]  = *(short4*)oqh;
  *(short4*)&qkv[base + 1024] = *(short4*)okl;
  *(short4*)&qkv[base + 1152] = *(short4*)okh;
}

// ---------------- banded attention, MFMA; 64 queries/block, 192-key window ----------------
__global__ __launch_bounds__(256, 2)
void attn_kernel(const short* __restrict__ qkv, const short* __restrict__ vT,
                 short* __restrict__ outp)
{
  __shared__ short lKV[256 * 72];   // K chunk (64x264) or V^T chunk (256x72)
  __shared__ short lP[64 * 200];    // P: 64 q-rows x 192 keys (+pad)
  const int tid  = threadIdx.x;
  const int lane = tid & 63, wave = tid >> 6;
  const int lhi  = lane >> 4, llo = lane & 15;
  const int i0 = blockIdx.x * 64;
  const int h = blockIdx.y, b = blockIdx.z;
  const int kw0 = i0 - 128;
  const size_t vbase = (size_t)(b * H_ + h) * HD_ * LTP_;

  short8 qf[8];
  {
    int ic = min(i0 + wave * 16 + llo, LT_ - 1);
    const short* qrow = qkv + (size_t)(b * LT_ + ic) * QKL_ + h * HD_;
#pragma unroll
    for (int ks = 0; ks < 8; ks++)
      qf[ks] = *(const short8*)(qrow + ks * 32 + lhi * 8);
  }

  f32x4 S[12];
#pragma unroll
  for (int st = 0; st < 12; st++) S[st] = f32x4{0.f, 0.f, 0.f, 0.f};

  for (int kc = 0; kc < 3; kc++) {
    if (kc) __syncthreads();
    {
      int row = tid >> 2;
      int jc = min(max(kw0 + kc * 64 + row, 0), LT_ - 1);
      const short* krow = qkv + (size_t)(b * LT_ + jc) * QKL_ + 1024 + h * HD_;
#pragma unroll
      for (int it = 0; it < 8; it++) {
        int seg = (tid & 3) + it * 4;
        *(short8*)&lKV[row * 264 + seg * 8] = *(const short8*)(krow + seg * 8);
      }
    }
    __syncthreads();
#pragma unroll
    for (int ks = 0; ks < 8; ks++) {
#pragma unroll
      for (int nt = 0; nt < 4; nt++) {
        short8 bf = *(const short8*)&lKV[(nt * 16 + llo) * 264 + ks * 32 + lhi * 8];
        S[kc * 4 + nt] = __builtin_amdgcn_mfma_f32_16x16x32_bf16(qf[ks], bf, S[kc * 4 + nt], 0, 0, 0);
      }
    }
  }

  const int irow = i0 + wave * 16 + lhi * 4;
  float mx[4], sm[4];
#pragma unroll
  for (int r = 0; r < 4; r++) mx[r] = -3.0e38f;
#pragma unroll
  for (int st = 0; st < 12; st++) {
    int j = kw0 + st * 16 + llo;
#pragma unroll
    for (int r = 0; r < 4; r++) {
      int i = irow + r;
      bool ok = (j >= 0) & (j <= i) & (j >= i - WIN_);
      float s = ok ? S[st][r] : -1.0e30f;
      S[st][r] = s;
      mx[r] = fmaxf(mx[r], s);
    }
  }
#pragma unroll
  for (int r = 0; r < 4; r++)
#pragma unroll
    for (int o = 1; o < 16; o <<= 1) mx[r] = fmaxf(mx[r], __shfl_xor(mx[r], o));
#pragma unroll
  for (int r = 0; r < 4; r++) sm[r] = 0.f;
#pragma unroll
  for (int st = 0; st < 12; st++)
#pragma unroll
    for (int r = 0; r < 4; r++) {
      float e = __expf(S[st][r] - mx[r]);
      S[st][r] = e;
      sm[r] += e;
    }
#pragma unroll
  for (int r = 0; r < 4; r++) {
#pragma unroll
    for (int o = 1; o < 16; o <<= 1) sm[r] += __shfl_xor(sm[r], o);
    sm[r] = 1.f / sm[r];
  }

#pragma unroll
  for (int st = 0; st < 12; st++)
#pragma unroll
    for (int r = 0; r < 4; r++)
      lP[(wave * 16 + lhi * 4 + r) * 200 + st * 16 + llo] = f2bf(S[st][r] * sm[r]);

  f32x4 O[16];
#pragma unroll
  for (int nt = 0; nt < 16; nt++) O[nt] = f32x4{0.f, 0.f, 0.f, 0.f};

  for (int kc = 0; kc < 3; kc++) {
    __syncthreads();
#pragma unroll
    for (int it = 0; it < 8; it++) {
      int id = it * 256 + tid;
      int d = id >> 3, seg = id & 7;
      int kbase = min(max(kw0 + kc * 64 + seg * 8, 0), LTP_ - 8);
      *(short8*)&lKV[d * 72 + seg * 8] = *(const short8*)&vT[vbase + (size_t)d * LTP_ + kbase];
    }
    __syncthreads();
#pragma unroll
    for (int ks = 0; ks < 2; ks++) {
      short8 pf = *(const short8*)&lP[(wave * 16 + llo) * 200 + kc * 64 + ks * 32 + lhi * 8];
#pragma unroll
      for (int nt = 0; nt < 16; nt++) {
        short8 vf = *(const short8*)&lKV[(nt * 16 + llo) * 72 + ks * 32 + lhi * 8];
        O[nt] = __builtin_amdgcn_mfma_f32_16x16x32_bf16(pf, vf, O[nt], 0, 0, 0);
      }
    }
  }

  short* orow = outp + (size_t)(b * LT_) * D_ + h * HD_;
#pragma unroll
  for (int nt = 0; nt < 16; nt++)
#pragma unroll
    for (int r = 0; r < 4; r++) {
      int i = irow + r;
      if (i < LT_) orow[(size_t)i * D_ + nt * 16 + llo] = f2bf(O[nt][r]);
    }
}

// ---------------- fused double-LN: x1 = res + LN1(mo); xn = bf16(LN2(x1)) ----------------
__global__ __launch_bounds__(256, 4)
void ln2_kernel(const float* __restrict__ mo, const float* __restrict__ xres,
                const float* __restrict__ g1, const float* __restrict__ b1,
                const float* __restrict__ g2, const float* __restrict__ b2,
                float* __restrict__ x1, short* __restrict__ xn)
{
  const int row = blockIdx.x;
  const int tid = threadIdx.x;
  const int lane = tid & 63, wave = tid >> 6;
  __shared__ float red[8], red2[8];
  float4 v = ((const float4*)(mo + (size_t)row * D_))[tid];
  float s = v.x + v.y + v.z + v.w;
  float s2 = v.x * v.x + v.y * v.y + v.z * v.z + v.w * v.w;
#pragma unroll
  for (int o = 1; o < 64; o <<= 1) { s += __shfl_xor(s, o); s2 += __shfl_xor(s2, o); }
  if (lane == 0) { red[wave] = s; red[wave + 4] = s2; }
  __syncthreads();
  float S = red[0] + red[1] + red[2] + red[3];
  float S2 = red[4] + red[5] + red[6] + red[7];
  float mu = S * (1.f / D_);
  float rs = rsqrtf(S2 * (1.f / D_) - mu * mu + 1e-5f);
  float4 gg = ((const float4*)g1)[tid];
  float4 bb = ((const float4*)b1)[tid];
  float4 xv = ((const float4*)(xres + (size_t)row * D_))[tid];
  float4 o1;
  o1.x = xv.x + (v.x - mu) * rs * gg.x + bb.x;
  o1.y = xv.y + (v.y - mu) * rs * gg.y + bb.y;
  o1.z = xv.z + (v.z - mu) * rs * gg.z + bb.z;
  o1.w = xv.w + (v.w - mu) * rs * gg.w + bb.w;
  ((float4*)(x1 + (size_t)row * D_))[tid] = o1;
  s = o1.x + o1.y + o1.z + o1.w;
  s2 = o1.x * o1.x + o1.y * o1.y + o1.z * o1.z + o1.w * o1.w;
#pragma unroll
  for (int o = 1; o < 64; o <<= 1) { s += __shfl_xor(s, o); s2 += __shfl_xor(s2, o); }
  if (lane == 0) { red2[wave] = s; red2[wave + 4] = s2; }
  __syncthreads();
  S = red2[0] + red2[1] + red2[2] + red2[3];
  S2 = red2[4] + red2[5] + red2[6] + red2[7];
  float mu2 = S * (1.f / D_);
  float rs2 = rsqrtf(S2 * (1.f / D_) - mu2 * mu2 + 1e-5f);
  float4 g2v = ((const float4*)g2)[tid];
  float4 b2v = ((const float4*)b2)[tid];
  short o2[4];
  o2[0] = f2bf((o1.x - mu2) * rs2 * g2v.x + b2v.x);
  o2[1] = f2bf((o1.y - mu2) * rs2 * g2v.y + b2v.y);
  o2[2] = f2bf((o1.z - mu2) * rs2 * g2v.z + b2v.z);
  o2[3] = f2bf((o1.w - mu2) * rs2 * g2v.w + b2v.w);
  *(short4*)&xn[(size_t)row * D_ + tid * 4] = *(short4*)o2;
}

// ---------------- host launcher ----------------
extern "C" void kernel_launch(void* const* d_in, const int* in_sizes, int n_in,
                              void* d_out, int out_size, void* d_ws, size_t ws_size,
                              hipStream_t stream)
{
  const float* x      = (const float*)d_in[0];
  const float* cosp   = (const float*)d_in[1];
  const float* sinp   = (const float*)d_in[2];
  const float* go     = (const float*)d_in[3];
  const float* lo     = (const float*)d_in[4];
  const float* wq     = (const float*)d_in[5];
  const float* wk     = (const float*)d_in[6];
  const float* wv     = (const float*)d_in[7];
  const float* wo     = (const float*)d_in[8];
  const float* pmem   = (const float*)d_in[9];
  const float* gate_w = (const float*)d_in[10];
  const float* gate_b = (const float*)d_in[11];
  const float* outp_w = (const float*)d_in[12];
  const float* outp_b = (const float*)d_in[13];
  const float* ln1g   = (const float*)d_in[14];
  const float* ln1b   = (const float*)d_in[15];
  const float* ln2g   = (const float*)d_in[16];
  const float* ln2b   = (const float*)d_in[17];
  const float* fc1w   = (const float*)d_in[18];
  const float* fc1b   = (const float*)d_in[19];
  const float* fc2w   = (const float*)d_in[20];
  const float* fc2b   = (const float*)d_in[21];
  float* out = (float*)d_out;
  char* p = (char*)d_ws;

  // ---- workspace layout (lifetime-aliased) ----
  short* wqkvT = (short*)(p + 0);          //  6,291,456 (3072 x 1024 bf16: q|k|v)
  short* woT   = (short*)(p + 6291456);    //  2,097,152
  short* gateT = (short*)(p + 8388608);    // 18,874,368
  short* outpT = (short*)(p + 27262976);   //  6,291,456
  short* fc1T  = (short*)(p + 33554432);   //  8,388,608
  short* fc2T  = (short*)(p + 41943040);   //  8,388,608
  short* comb  = (short*)(p + 50331648);   // 50,331,648 (8192x3072 bf16)
  char*  pool  = p + 100663296;
  short* xp    = (short*)(pool);                   // 16,793,600 (8200x1024 bf16)
  short* qkv   = (short*)(pool + 16793600);        // 33,587,200 (8200x2048 bf16, q|k)
  short* vT    = (short*)(pool + 67174400);        // 16,842,752 (8 x 256 x 4112 bf16)
  short* a_o   = (short*)(pool + 84017152);        // 16,793,600
  // aliases (lifetimes disjoint):
  short* gated = (short*)(pool);                   // after core GEMM: over xp/qkv
  short* h1    = (short*)(pool);                   // after outproj: over xp..qkv
  float* mo    = (float*)(pool + 67174400);        // after attention: over vT+a_o
  float* x1    = (float*)(comb);                   // after gate GEMM: over comb
  short* xn    = (short*)((char*)comb + 33554432); // within old comb region

  // 1) all weight transposes in ONE launch
  TAll t;
  const float* srcs[8] = {wq, wk, wv, wo, gate_w, outp_w, fc1w, fc2w};
  short* dsts[8] = {wqkvT, wqkvT + 1048576, wqkvT + 2097152, woT, gateT, outpT, fc1T, fc2T};
  const int Rs[8] = {1024, 1024, 1024, 1024, 3072, 3072, 1024, 4096};
  const int Cs[8] = {1024, 1024, 1024, 1024, 3072, 1024, 4096, 1024};
  int cum = 0;
  for (int i = 0; i < 8; i++) {
    t.src[i] = srcs[i]; t.dst[i] = dsts[i];
    t.R[i] = Rs[i]; t.C[i] = Cs[i]; t.nbx[i] = Cs[i] / 32;
    t.start[i] = cum;
    cum += (Cs[i] / 32) * (Rs[i] / 32);
  }
  transpose_all<<<cum, 256, 0, stream>>>(t);   // cum = 24576

  // 2) xp = [pmem; x] bf16 AND combined[:, :2048] (fused)
  prep_k<<<24584, 256, 0, stream>>>(x, pmem, go, lo, xp, comb);

  // 3a) fused QK projection (bf16 out, ldc=2048)
  const int Mq = B_ * LT_;   // 8200
  gemm_bt<EP_BF16, 128><<<dim3(65, 16), 256, 0, stream>>>(xp, 1024, wqkvT, qkv, QKL_, nullptr, nullptr, 0, Mq, 2048, 1024);
  // 3b) V^T = Wv^T . Xp^T, written directly into (B,H,HD,LTP) layout.
  //     N=8200 padded to 8320: B-row overrun reads ~244KB into qkv (allocated; masked at write).
  gemm_bt<EP_VT, 64><<<dim3(16, 65), 256, 0, stream>>>(wqkvT + 2097152, 1024, xp, vT, LTP_, nullptr, nullptr, 0, 1024, 8200, 1024);

  // 4) RoPE in-place on q,k (q scaled by 1/16)
  rope_kernel<<<4100, 256, 0, stream>>>(qkv, cosp, sinp);

  // 5) banded attention
  attn_kernel<<<dim3(65, H_, B_), 256, 0, stream>>>(qkv, vT, a_o);

  // 6) core_out = (attn @ wo) with pmem rows skipped -> combined[:, 2048:]
  gemm_bt<EP_CORE, 64><<<dim3(129, 8), 256, 0, stream>>>(
      a_o, 1024, woT, comb + 2048, 3072, nullptr, nullptr, 0, Mq, 1024, 1024);

  // 7) gated = combined * sigmoid(combined @ gate_w + gate_b)
  gemm_bt<EP_GATE, 128><<<dim3(64, 24), 256, 0, stream>>>(comb, 3072, gateT, gated, 3072, gate_b, comb, 3072, 8192, 3072, 3072);

  // 8) memory_output = gated @ outproj_w + b (f32)
  gemm_bt<EP_F32B, 64><<<dim3(128, 8), 256, 0, stream>>>(gated, 3072, outpT, mo, 1024, outp_b, nullptr, 0, 8192, 1024, 3072);

  // 9) x1 = x + LN1(mo); xn = bf16(LN2(x1))
  ln2_kernel<<<8192, 256, 0, stream>>>(mo, x, ln1g, ln1b, ln2g, ln2b, x1, xn);

  // 10) MLP: h1 = silu(xn @ fc1 + b1); out = x1 + h1 @ fc2 + b2
  gemm_bt<EP_SILU, 128><<<dim3(64, 32), 256, 0, stream>>>(xn, 1024, fc1T, h1, 4096, fc1b, nullptr, 0, 8192, 4096, 1024);
  gemm_bt<EP_RES, 64><<<dim3(128, 8), 256, 0, stream>>>(h1, 4096, fc2T, out, 1024, fc2b, x1, 1024, 8192, 1024, 4096);
}

// Round 6
// 921.430 us; speedup vs baseline: 1.1382x; 1.0517x over previous
//
#include <hip/hip_runtime.h>
#include <stdint.h>

// ---------------- problem constants ----------------
#define D_    1024
#define H_    4
#define HD_   256
#define WIN_  128
#define NPM_  4
#define B_    2
#define L_    4096
#define LT_   4100     // L + NPMEM
#define LTP_  4112     // padded row length for V^T (16B-aligned rows)
#define QKL_  2048     // fused qk row stride (v is produced directly as V^T)

typedef __attribute__((ext_vector_type(8))) short short8;   // 8 bf16 (4 VGPRs)
typedef __attribute__((ext_vector_type(4))) float f32x4;    // MFMA acc

__device__ __forceinline__ short f2bf(float f) {
  union { float f; uint32_t u; } v; v.f = f;
  uint32_t r = v.u + 0x7FFFu + ((v.u >> 16) & 1u);   // RNE
  return (short)(r >> 16);
}
__device__ __forceinline__ float bf2f(short h) {
  union { uint32_t u; float f; } v; v.u = ((uint32_t)(uint16_t)h) << 16;
  return v.f;
}

// ---- async global->LDS (16B per lane; dest = wave-uniform base + lane*16) ----
typedef __attribute__((address_space(1))) void GAS;
typedef __attribute__((address_space(3))) void LAS;
__device__ __forceinline__ void gl16(const void* g, void* l) {
  __builtin_amdgcn_global_load_lds((GAS*)g, (LAS*)l, 16, 0, 0);
}
__device__ __forceinline__ void waitvm0() { asm volatile("s_waitcnt vmcnt(0)" ::: "memory"); }

// epilogue kinds
#define EP_BF16 0   // store bf16, no bias
#define EP_F32B 1   // store f32 + bias
#define EP_GATE 2   // g=sigmoid(acc+bias); store bf16( aux_bf16[r][c] * g )
#define EP_SILU 3   // v=acc+bias; store bf16( v*sigmoid(v) )
#define EP_RES  4   // store f32( acc + bias + aux_f32[r][c] )
#define EP_CORE 5   // store bf16, skipping pmem rows: row b*LT+t -> b*L+(t-NPM)
#define EP_VT   6   // V^T producer: row gr=(h*256+dd), col gc=token -> vT[(b,h,dd,tok)]

// ---------------- 128-tile GEMM: C(MxN) = A(MxK) * B^T(NxK), bf16 in, f32 acc ----
// m97-replica: 2 LDS buffers (32 KB -> 3-4 blocks/CU TLP), global_load_lds
// width-16 staging, stage issued before frag reads, vmcnt(0)+__syncthreads per
// K-step. Zero-conflict XOR swizzle applied on the GLOBAL source side; LDS dest
// linear in tid. All production GEMMs use TM=128 (16 MFMA : 8 ds_read : 4 gl16
// per wave per K-step -- best MFMA ratio; TM=64's 8:6:3 measured ~30% slower).
template<int EP, int TM>
__global__ __launch_bounds__(256, 4)
void gemm_bt(const short* __restrict__ A, int lda,
             const short* __restrict__ Bt,
             void* __restrict__ Cp, int ldc,
             const float* __restrict__ bias,
             const void* __restrict__ aux, int ldaux,
             int M, int N, int K)
{
  constexpr int WM = TM / 2;          // wave rows
  constexpr int MT = WM / 16;         // m-frags per wave
  constexpr int BUFSZ = (TM + 128) * 32;   // shorts per LDS buffer (A tile + B tile)
  __shared__ __attribute__((aligned(16))) short lds[2 * BUFSZ];
  const int tid  = threadIdx.x;
  const int lane = tid & 63, wave = tid >> 6;
  const int lhi  = lane >> 4, llo = lane & 15;
  const int m0 = blockIdx.x * TM, n0 = blockIdx.y * 128;
  const int mw = (wave >> 1) * WM, nw = (wave & 1) * 64;

  // staging: LDS row = tid>>2 (64B rows), phys seg = tid&3 holds global seg
  // (tid&3)^((tid>>3)&3); frag read recovers with lhi ^ ((llo>>1)&3).
  const int srow = tid >> 2;                       // 0..63
  const int sg   = (tid & 3) ^ ((tid >> 3) & 3);   // swizzled global 16B-seg
  const short* pA0 = A + (size_t)min(m0 + srow, M - 1) * lda + sg * 8;
  const short* pA1 = (TM == 128) ? A + (size_t)min(m0 + srow + 64, M - 1) * lda + sg * 8 : pA0;
  // NOTE (EP_VT): B rows may run past N up to the 128-pad; callers guarantee the
  // overrun stays inside the workspace (reads are garbage, masked at write).
  const short* pB0 = Bt + (size_t)(n0 + srow) * K + sg * 8;
  const short* pB1 = Bt + (size_t)(n0 + srow + 64) * K + sg * 8;

  const int segoff = (lhi ^ ((llo >> 1) & 3)) * 8;  // frag-read swizzle

  auto stage = [&](int b, int i) {
    const int k = i << 5;
    short* base = &lds[b * BUFSZ];
    gl16(pA0 + k, &base[tid * 8]);                          // A rows 0..63
    if constexpr (TM == 128) gl16(pA1 + k, &base[2048 + tid * 8]);  // A rows 64..127
    gl16(pB0 + k, &base[TM * 32 + tid * 8]);                // B rows 0..63
    gl16(pB1 + k, &base[TM * 32 + 2048 + tid * 8]);         // B rows 64..127
  };

  f32x4 acc[MT][4];
#pragma unroll
  for (int i = 0; i < MT; i++)
#pragma unroll
    for (int j = 0; j < 4; j++) acc[i][j] = f32x4{0.f, 0.f, 0.f, 0.f};

  const int NI = K >> 5;
  stage(0, 0);
  waitvm0();
  __syncthreads();

  for (int i = 0; i < NI; i++) {
    if (i + 1 < NI) stage((i + 1) & 1, i + 1);   // issue-early: loads fly over MFMA
    const short* bufp = &lds[(i & 1) * BUFSZ];
    short8 af[MT], bfr[4];
#pragma unroll
    for (int mt = 0; mt < MT; mt++)
      af[mt] = *(const short8*)&bufp[(mw + mt * 16 + llo) * 32 + segoff];
#pragma unroll
    for (int nt = 0; nt < 4; nt++)
      bfr[nt] = *(const short8*)&bufp[TM * 32 + (nw + nt * 16 + llo) * 32 + segoff];
#pragma unroll
    for (int mt = 0; mt < MT; mt++)
#pragma unroll
      for (int nt = 0; nt < 4; nt++)
        acc[mt][nt] = __builtin_amdgcn_mfma_f32_16x16x32_bf16(af[mt], bfr[nt], acc[mt][nt], 0, 0, 0);
    waitvm0();           // next buffer landed (drain covered by other blocks' waves)
    __syncthreads();     // + lgkm drain: all waves' reads of buf i complete
  }

  const int gcb = n0 + nw;
#pragma unroll
  for (int mt = 0; mt < MT; mt++) {
    const int gr0 = m0 + mw + mt * 16 + lhi * 4;
#pragma unroll
    for (int nt = 0; nt < 4; nt++) {
      const int gc = gcb + nt * 16 + llo;
      float bv = 0.f;
      if constexpr (EP != EP_BF16 && EP != EP_CORE && EP != EP_VT) bv = bias[gc];
#pragma unroll
      for (int r = 0; r < 4; r++) {
        const int gr = gr0 + r;
        if (gr >= M) continue;
        const float v = acc[mt][nt][r];
        if constexpr (EP == EP_VT) {
          // gr = h*256+dd (M=1024), gc = global token col (N=8200, 128-padded)
          if (gc < N) {
            const int b   = gc >= LT_ ? 1 : 0;
            const int tok = gc - b * LT_;
            const int hh  = gr >> 8, dd = gr & 255;
            ((short*)Cp)[(size_t)((b * H_ + hh) * HD_ + dd) * ldc + tok] = f2bf(v);
          }
          continue;
        }
        if constexpr (EP == EP_CORE) {
          const int b   = gr >= LT_ ? 1 : 0;
          const int tok = gr - b * LT_;
          if (tok >= NPM_) {
            const int cr = b * L_ + (tok - NPM_);
            ((short*)Cp)[(size_t)cr * ldc + gc] = f2bf(v);
          }
          continue;
        }
        const size_t idx = (size_t)gr * ldc + gc;
        if constexpr (EP == EP_BF16) {
          ((short*)Cp)[idx] = f2bf(v);
        } else if constexpr (EP == EP_F32B) {
          ((float*)Cp)[idx] = v + bv;
        } else if constexpr (EP == EP_GATE) {
          float g  = 1.f / (1.f + __expf(-(v + bv)));
          float cv = bf2f(((const short*)aux)[(size_t)gr * ldaux + gc]);
          ((short*)Cp)[idx] = f2bf(cv * g);
        } else if constexpr (EP == EP_SILU) {
          float xx = v + bv;
          ((short*)Cp)[idx] = f2bf(xx / (1.f + __expf(-xx)));
        } else {
          ((float*)Cp)[idx] = v + bv + ((const float*)aux)[(size_t)gr * ldaux + gc];
        }
      }
    }
  }
}

// ---------------- fused cast+transpose of ALL weights (one launch) ----------------
struct TAll {
  const float* src[8];
  short* dst[8];
  int C[8];     // src cols (ld_in)
  int R[8];     // src rows (ld_out)
  int nbx[8];   // C/32
  int start[8]; // cumulative block offsets
};

__global__ __launch_bounds__(256)
void transpose_all(TAll t)
{
  __shared__ short tile[32][33];
  const int bid = blockIdx.x;
  int w = 0;
#pragma unroll
  for (int i = 1; i < 8; i++) w = (bid >= t.start[i]) ? i : w;
  const int rel = bid - t.start[w];
  const int nbx = t.nbx[w];
  const int bx = rel % nbx, by = rel / nbx;
  const float* src = t.src[w];
  short* dst = t.dst[w];
  const int ld_in = t.C[w], ld_out = t.R[w];
  const int r0 = by * 32, c0 = bx * 32;
  const int tx = threadIdx.x & 31, ty = threadIdx.x >> 5;
#pragma unroll
  for (int i = 0; i < 4; i++)
    tile[ty + i * 8][tx] = f2bf(src[(size_t)(r0 + ty + i * 8) * ld_in + c0 + tx]);
  __syncthreads();
#pragma unroll
  for (int i = 0; i < 4; i++)
    dst[(size_t)(c0 + ty + i * 8) * ld_out + r0 + tx] = tile[tx][ty + i * 8];
}

// ---------------- fused prep: xp = [pmem;x] bf16  AND  combined[:, :2048] ----------------
// blocks 0..8199: xp rows; blocks 8200..24583: comb rows.
__global__ __launch_bounds__(256)
void prep_k(const float* __restrict__ x, const float* __restrict__ pmem,
            const float* __restrict__ go, const float* __restrict__ lo,
            short* __restrict__ xp, short* __restrict__ comb)
{
  const int bid = blockIdx.x;
  if (bid < 8200) {
    int gid = bid * 256 + threadIdx.x;
    int row = gid >> 8;
    int c4  = (gid & 255) * 4;
    int b   = row >= LT_ ? 1 : 0;
    int tok = row - b * LT_;
    const float* src = (tok < NPM_) ? (pmem + (size_t)tok * D_ + c4)
                                    : (x + ((size_t)b * L_ + tok - NPM_) * D_ + c4);
    float4 v = *(const float4*)src;
    short o[4] = {f2bf(v.x), f2bf(v.y), f2bf(v.z), f2bf(v.w)};
    *(short4*)&xp[(size_t)row * D_ + c4] = *(short4*)o;
  } else {
    int gid = (bid - 8200) * 256 + threadIdx.x;
    int row = gid >> 9;
    int c4  = (gid & 511) * 4;
    const float* src = (c4 < D_) ? (go + (size_t)row * D_ + c4)
                                 : (lo + (size_t)row * D_ + (c4 - D_));
    float4 v = *(const float4*)src;
    short o[4] = {f2bf(v.x), f2bf(v.y), f2bf(v.z), f2bf(v.w)};
    *(short4*)&comb[(size_t)row * 3072 + c4] = *(short4*)o;
  }
}

// ---------------- in-place RoPE on fused qk (bf16); folds 1/sqrt(HD) into q ----------------
__global__ __launch_bounds__(256)
void rope_kernel(short* __restrict__ qkv,
                 const float* __restrict__ cosp, const float* __restrict__ sinp)
{
  int gid = blockIdx.x * 256 + threadIdx.x;       // 8200 rows * 4 heads * 32 quads; exact
  int d   = (gid & 31) * 4;
  int h   = (gid >> 5) & 3;
  int row = gid >> 7;
  int t   = row >= LT_ ? row - LT_ : row;
  size_t base = (size_t)row * QKL_ + h * HD_ + d;
  float4 cl = *(const float4*)&cosp[(size_t)t * HD_ + d];
  float4 ch = *(const float4*)&cosp[(size_t)t * HD_ + d + 128];
  float4 sl = *(const float4*)&sinp[(size_t)t * HD_ + d];
  float4 sh = *(const float4*)&sinp[(size_t)t * HD_ + d + 128];
  short4 ql4 = *(const short4*)&qkv[base],        qh4 = *(const short4*)&qkv[base + 128];
  short4 kl4 = *(const short4*)&qkv[base + 1024], kh4 = *(const short4*)&qkv[base + 1152];
  const float SC = 1.f / 16.f;   // 1/sqrt(256)
  short oql[4], oqh[4], okl[4], okh[4];
#pragma unroll
  for (int j = 0; j < 4; j++) {
    float c0 = ((float*)&cl)[j], c1 = ((float*)&ch)[j];
    float s0 = ((float*)&sl)[j], s1 = ((float*)&sh)[j];
    float ql = bf2f(((short*)&ql4)[j]), qh = bf2f(((short*)&qh4)[j]);
    float kl = bf2f(((short*)&kl4)[j]), kh = bf2f(((short*)&kh4)[j]);
    oql[j] = f2bf((ql * c0 - qh * s0) * SC);
    oqh[j] = f2bf((qh * c1 + ql * s1) * SC);
    okl[j] = f2bf(kl * c0 - kh * s0);
    okh[j] = f2bf(kh * c1 + kl * s1);
  }
  *(short4*)&qkv[base]        = *(short4*)oql;
  *(short4*)&qkv[base + 128]  = *(short4*)oqh;
  *(short4*)&qkv[base + 1024] = *(short4*)okl;
  *(short4*)&qkv[base + 1152] = *(short4*)okh;
}

// ---------------- banded attention, MFMA; 64 queries/block, 192-key window ----------------
__global__ __launch_bounds__(256, 2)
void attn_kernel(const short* __restrict__ qkv, const short* __restrict__ vT,
                 short* __restrict__ outp)
{
  __shared__ short lKV[256 * 72];   // K chunk (64x264) or V^T chunk (256x72)
  __shared__ short lP[64 * 200];    // P: 64 q-rows x 192 keys (+pad)
  const int tid  = threadIdx.x;
  const int lane = tid & 63, wave = tid >> 6;
  const int lhi  = lane >> 4, llo = lane & 15;
  const int i0 = blockIdx.x * 64;
  const int h = blockIdx.y, b = blockIdx.z;
  const int kw0 = i0 - 128;
  const size_t vbase = (size_t)(b * H_ + h) * HD_ * LTP_;

  short8 qf[8];
  {
    int ic = min(i0 + wave * 16 + llo, LT_ - 1);
    const short* qrow = qkv + (size_t)(b * LT_ + ic) * QKL_ + h * HD_;
#pragma unroll
    for (int ks = 0; ks < 8; ks++)
      qf[ks] = *(const short8*)(qrow + ks * 32 + lhi * 8);
  }

  f32x4 S[12];
#pragma unroll
  for (int st = 0; st < 12; st++) S[st] = f32x4{0.f, 0.f, 0.f, 0.f};

  for (int kc = 0; kc < 3; kc++) {
    if (kc) __syncthreads();
    {
      int row = tid >> 2;
      int jc = min(max(kw0 + kc * 64 + row, 0), LT_ - 1);
      const short* krow = qkv + (size_t)(b * LT_ + jc) * QKL_ + 1024 + h * HD_;
#pragma unroll
      for (int it = 0; it < 8; it++) {
        int seg = (tid & 3) + it * 4;
        *(short8*)&lKV[row * 264 + seg * 8] = *(const short8*)(krow + seg * 8);
      }
    }
    __syncthreads();
#pragma unroll
    for (int ks = 0; ks < 8; ks++) {
#pragma unroll
      for (int nt = 0; nt < 4; nt++) {
        short8 bf = *(const short8*)&lKV[(nt * 16 + llo) * 264 + ks * 32 + lhi * 8];
        S[kc * 4 + nt] = __builtin_amdgcn_mfma_f32_16x16x32_bf16(qf[ks], bf, S[kc * 4 + nt], 0, 0, 0);
      }
    }
  }

  const int irow = i0 + wave * 16 + lhi * 4;
  float mx[4], sm[4];
#pragma unroll
  for (int r = 0; r < 4; r++) mx[r] = -3.0e38f;
#pragma unroll
  for (int st = 0; st < 12; st++) {
    int j = kw0 + st * 16 + llo;
#pragma unroll
    for (int r = 0; r < 4; r++) {
      int i = irow + r;
      bool ok = (j >= 0) & (j <= i) & (j >= i - WIN_);
      float s = ok ? S[st][r] : -1.0e30f;
      S[st][r] = s;
      mx[r] = fmaxf(mx[r], s);
    }
  }
#pragma unroll
  for (int r = 0; r < 4; r++)
#pragma unroll
    for (int o = 1; o < 16; o <<= 1) mx[r] = fmaxf(mx[r], __shfl_xor(mx[r], o));
#pragma unroll
  for (int r = 0; r < 4; r++) sm[r] = 0.f;
#pragma unroll
  for (int st = 0; st < 12; st++)
#pragma unroll
    for (int r = 0; r < 4; r++) {
      float e = __expf(S[st][r] - mx[r]);
      S[st][r] = e;
      sm[r] += e;
    }
#pragma unroll
  for (int r = 0; r < 4; r++) {
#pragma unroll
    for (int o = 1; o < 16; o <<= 1) sm[r] += __shfl_xor(sm[r], o);
    sm[r] = 1.f / sm[r];
  }

#pragma unroll
  for (int st = 0; st < 12; st++)
#pragma unroll
    for (int r = 0; r < 4; r++)
      lP[(wave * 16 + lhi * 4 + r) * 200 + st * 16 + llo] = f2bf(S[st][r] * sm[r]);

  f32x4 O[16];
#pragma unroll
  for (int nt = 0; nt < 16; nt++) O[nt] = f32x4{0.f, 0.f, 0.f, 0.f};

  for (int kc = 0; kc < 3; kc++) {
    __syncthreads();
#pragma unroll
    for (int it = 0; it < 8; it++) {
      int id = it * 256 + tid;
      int d = id >> 3, seg = id & 7;
      int kbase = min(max(kw0 + kc * 64 + seg * 8, 0), LTP_ - 8);
      *(short8*)&lKV[d * 72 + seg * 8] = *(const short8*)&vT[vbase + (size_t)d * LTP_ + kbase];
    }
    __syncthreads();
#pragma unroll
    for (int ks = 0; ks < 2; ks++) {
      short8 pf = *(const short8*)&lP[(wave * 16 + llo) * 200 + kc * 64 + ks * 32 + lhi * 8];
#pragma unroll
      for (int nt = 0; nt < 16; nt++) {
        short8 vf = *(const short8*)&lKV[(nt * 16 + llo) * 72 + ks * 32 + lhi * 8];
        O[nt] = __builtin_amdgcn_mfma_f32_16x16x32_bf16(pf, vf, O[nt], 0, 0, 0);
      }
    }
  }

  short* orow = outp + (size_t)(b * LT_) * D_ + h * HD_;
#pragma unroll
  for (int nt = 0; nt < 16; nt++)
#pragma unroll
    for (int r = 0; r < 4; r++) {
      int i = irow + r;
      if (i < LT_) orow[(size_t)i * D_ + nt * 16 + llo] = f2bf(O[nt][r]);
    }
}

// ---------------- fused double-LN: x1 = res + LN1(mo); xn = bf16(LN2(x1)) ----------------
__global__ __launch_bounds__(256, 4)
void ln2_kernel(const float* __restrict__ mo, const float* __restrict__ xres,
                const float* __restrict__ g1, const float* __restrict__ b1,
                const float* __restrict__ g2, const float* __restrict__ b2,
                float* __restrict__ x1, short* __restrict__ xn)
{
  const int row = blockIdx.x;
  const int tid = threadIdx.x;
  const int lane = tid & 63, wave = tid >> 6;
  __shared__ float red[8], red2[8];
  float4 v = ((const float4*)(mo + (size_t)row * D_))[tid];
  float s = v.x + v.y + v.z + v.w;
  float s2 = v.x * v.x + v.y * v.y + v.z * v.z + v.w * v.w;
#pragma unroll
  for (int o = 1; o < 64; o <<= 1) { s += __shfl_xor(s, o); s2 += __shfl_xor(s2, o); }
  if (lane == 0) { red[wave] = s; red[wave + 4] = s2; }
  __syncthreads();
  float S = red[0] + red[1] + red[2] + red[3];
  float S2 = red[4] + red[5] + red[6] + red[7];
  float mu = S * (1.f / D_);
  float rs = rsqrtf(S2 * (1.f / D_) - mu * mu + 1e-5f);
  float4 gg = ((const float4*)g1)[tid];
  float4 bb = ((const float4*)b1)[tid];
  float4 xv = ((const float4*)(xres + (size_t)row * D_))[tid];
  float4 o1;
  o1.x = xv.x + (v.x - mu) * rs * gg.x + bb.x;
  o1.y = xv.y + (v.y - mu) * rs * gg.y + bb.y;
  o1.z = xv.z + (v.z - mu) * rs * gg.z + bb.z;
  o1.w = xv.w + (v.w - mu) * rs * gg.w + bb.w;
  ((float4*)(x1 + (size_t)row * D_))[tid] = o1;
  s = o1.x + o1.y + o1.z + o1.w;
  s2 = o1.x * o1.x + o1.y * o1.y + o1.z * o1.z + o1.w * o1.w;
#pragma unroll
  for (int o = 1; o < 64; o <<= 1) { s += __shfl_xor(s, o); s2 += __shfl_xor(s2, o); }
  if (lane == 0) { red2[wave] = s; red2[wave + 4] = s2; }
  __syncthreads();
  S = red2[0] + red2[1] + red2[2] + red2[3];
  S2 = red2[4] + red2[5] + red2[6] + red2[7];
  float mu2 = S * (1.f / D_);
  float rs2 = rsqrtf(S2 * (1.f / D_) - mu2 * mu2 + 1e-5f);
  float4 g2v = ((const float4*)g2)[tid];
  float4 b2v = ((const float4*)b2)[tid];
  short o2[4];
  o2[0] = f2bf((o1.x - mu2) * rs2 * g2v.x + b2v.x);
  o2[1] = f2bf((o1.y - mu2) * rs2 * g2v.y + b2v.y);
  o2[2] = f2bf((o1.z - mu2) * rs2 * g2v.z + b2v.z);
  o2[3] = f2bf((o1.w - mu2) * rs2 * g2v.w + b2v.w);
  *(short4*)&xn[(size_t)row * D_ + tid * 4] = *(short4*)o2;
}

// ---------------- host launcher ----------------
extern "C" void kernel_launch(void* const* d_in, const int* in_sizes, int n_in,
                              void* d_out, int out_size, void* d_ws, size_t ws_size,
                              hipStream_t stream)
{
  const float* x      = (const float*)d_in[0];
  const float* cosp   = (const float*)d_in[1];
  const float* sinp   = (const float*)d_in[2];
  const float* go     = (const float*)d_in[3];
  const float* lo     = (const float*)d_in[4];
  const float* wq     = (const float*)d_in[5];
  const float* wk     = (const float*)d_in[6];
  const float* wv     = (const float*)d_in[7];
  const float* wo     = (const float*)d_in[8];
  const float* pmem   = (const float*)d_in[9];
  const float* gate_w = (const float*)d_in[10];
  const float* gate_b = (const float*)d_in[11];
  const float* outp_w = (const float*)d_in[12];
  const float* outp_b = (const float*)d_in[13];
  const float* ln1g   = (const float*)d_in[14];
  const float* ln1b   = (const float*)d_in[15];
  const float* ln2g   = (const float*)d_in[16];
  const float* ln2b   = (const float*)d_in[17];
  const float* fc1w   = (const float*)d_in[18];
  const float* fc1b   = (const float*)d_in[19];
  const float* fc2w   = (const float*)d_in[20];
  const float* fc2b   = (const float*)d_in[21];
  float* out = (float*)d_out;
  char* p = (char*)d_ws;

  // ---- workspace layout (lifetime-aliased) ----
  short* wqkvT = (short*)(p + 0);          //  6,291,456 (3072 x 1024 bf16: q|k|v)
  short* woT   = (short*)(p + 6291456);    //  2,097,152
  short* gateT = (short*)(p + 8388608);    // 18,874,368
  short* outpT = (short*)(p + 27262976);   //  6,291,456
  short* fc1T  = (short*)(p + 33554432);   //  8,388,608
  short* fc2T  = (short*)(p + 41943040);   //  8,388,608
  short* comb  = (short*)(p + 50331648);   // 50,331,648 (8192x3072 bf16)
  char*  pool  = p + 100663296;
  short* xp    = (short*)(pool);                   // 16,793,600 (8200x1024 bf16)
  short* qkv   = (short*)(pool + 16793600);        // 33,587,200 (8200x2048 bf16, q|k)
  short* vT    = (short*)(pool + 67174400);        // 16,842,752 (8 x 256 x 4112 bf16)
  short* a_o   = (short*)(pool + 84017152);        // 16,793,600
  // aliases (lifetimes disjoint):
  short* gated = (short*)(pool);                   // after core GEMM: over xp/qkv
  short* h1    = (short*)(pool);                   // after outproj: over xp..qkv
  float* mo    = (float*)(pool + 67174400);        // after attention: over vT+a_o
  float* x1    = (float*)(comb);                   // after gate GEMM: over comb
  short* xn    = (short*)((char*)comb + 33554432); // within old comb region

  // 1) all weight transposes in ONE launch
  TAll t;
  const float* srcs[8] = {wq, wk, wv, wo, gate_w, outp_w, fc1w, fc2w};
  short* dsts[8] = {wqkvT, wqkvT + 1048576, wqkvT + 2097152, woT, gateT, outpT, fc1T, fc2T};
  const int Rs[8] = {1024, 1024, 1024, 1024, 3072, 3072, 1024, 4096};
  const int Cs[8] = {1024, 1024, 1024, 1024, 3072, 1024, 4096, 1024};
  int cum = 0;
  for (int i = 0; i < 8; i++) {
    t.src[i] = srcs[i]; t.dst[i] = dsts[i];
    t.R[i] = Rs[i]; t.C[i] = Cs[i]; t.nbx[i] = Cs[i] / 32;
    t.start[i] = cum;
    cum += (Cs[i] / 32) * (Rs[i] / 32);
  }
  transpose_all<<<cum, 256, 0, stream>>>(t);   // cum = 24576

  // 2) xp = [pmem; x] bf16 AND combined[:, :2048] (fused)
  prep_k<<<24584, 256, 0, stream>>>(x, pmem, go, lo, xp, comb);

  // 3a) fused QK projection (bf16 out, ldc=2048)
  const int Mq = B_ * LT_;   // 8200
  gemm_bt<EP_BF16, 128><<<dim3(65, 16), 256, 0, stream>>>(xp, 1024, wqkvT, qkv, QKL_, nullptr, nullptr, 0, Mq, 2048, 1024);
  // 3b) V^T = Wv^T . Xp^T, written directly into (B,H,HD,LTP) layout.
  //     N=8200 padded to 8320: B-row overrun reads ~244KB into qkv (allocated; masked at write).
  gemm_bt<EP_VT, 128><<<dim3(8, 65), 256, 0, stream>>>(wqkvT + 2097152, 1024, xp, vT, LTP_, nullptr, nullptr, 0, 1024, 8200, 1024);

  // 4) RoPE in-place on q,k (q scaled by 1/16)
  rope_kernel<<<4100, 256, 0, stream>>>(qkv, cosp, sinp);

  // 5) banded attention
  attn_kernel<<<dim3(65, H_, B_), 256, 0, stream>>>(qkv, vT, a_o);

  // 6) core_out = (attn @ wo) with pmem rows skipped -> combined[:, 2048:]
  gemm_bt<EP_CORE, 128><<<dim3(65, 8), 256, 0, stream>>>(
      a_o, 1024, woT, comb + 2048, 3072, nullptr, nullptr, 0, Mq, 1024, 1024);

  // 7) gated = combined * sigmoid(combined @ gate_w + gate_b)
  gemm_bt<EP_GATE, 128><<<dim3(64, 24), 256, 0, stream>>>(comb, 3072, gateT, gated, 3072, gate_b, comb, 3072, 8192, 3072, 3072);

  // 8) memory_output = gated @ outproj_w + b (f32)
  gemm_bt<EP_F32B, 128><<<dim3(64, 8), 256, 0, stream>>>(gated, 3072, outpT, mo, 1024, outp_b, nullptr, 0, 8192, 1024, 3072);

  // 9) x1 = x + LN1(mo); xn = bf16(LN2(x1))
  ln2_kernel<<<8192, 256, 0, stream>>>(mo, x, ln1g, ln1b, ln2g, ln2b, x1, xn);

  // 10) MLP: h1 = silu(xn @ fc1 + b1); out = x1 + h1 @ fc2 + b2
  gemm_bt<EP_SILU, 128><<<dim3(64, 32), 256, 0, stream>>>(xn, 1024, fc1T, h1, 4096, fc1b, nullptr, 0, 8192, 4096, 1024);
  gemm_bt<EP_RES, 128><<<dim3(64, 8), 256, 0, stream>>>(h1, 4096, fc2T, out, 1024, fc2b, x1, 1024, 8192, 1024, 4096);
}